// Round 7
// baseline (596.297 us; speedup 1.0000x reference)
//
#include <hip/hip_runtime.h>
#include <hip/hip_bf16.h>

typedef unsigned short u16;
typedef unsigned int u32;
typedef __attribute__((ext_vector_type(8))) short bf16x8;
typedef __attribute__((ext_vector_type(4))) float f32x4;

#define NN 20000
#define NE 320000

// ---------------- workspace layout (padded CSR; ws_size >= 3,012,224 proven) ----------------
#define WP_H     256       // 640 f32
#define WP_U1    3072      // 36 f32
#define WP_U2    3328      // 180 f32
#define WP_U3    4096      // 660 f32
#define WP_CUR   7168      // 20000 i32 (doubles as deg for k_main)
#define WP_POSF  87168     // 20000 float4
#define WP_WB    407168    // 22528 u16
#define WP_EL16  452224    // 20000*64 u16

__device__ __forceinline__ float bf2f(u16 u){ return __uint_as_float(((u32)u) << 16); }
__device__ __forceinline__ u16 f2bf(float f){
  u32 u = __float_as_uint(f);
  u32 r = (u + 0x7fffu + ((u >> 16) & 1u)) >> 16;
  return (u16)r;
}
__device__ __forceinline__ u16 f2bfa(float f){
  return (u16)((__float_as_uint(f) + 0x8000u) >> 16);
}
__device__ __forceinline__ u32 pk2bf(float a, float b){
  __hip_bfloat162 h = __float22bfloat162_rn(make_float2(a, b));
  return *(u32*)&h;
}
__device__ __forceinline__ float silu_f(float v){
  return v * __builtin_amdgcn_rcpf(1.0f + __expf(-v));
}
__device__ __forceinline__ float ldf(const void* p, int i, int bf){
  return bf ? bf2f(((const u16*)p)[i]) : ((const float*)p)[i];
}
__device__ __forceinline__ f32x4 mfma16(bf16x8 a, bf16x8 b, f32x4 c){
  return __builtin_amdgcn_mfma_f32_16x16x32_bf16(a, b, c, 0, 0, 0);
}

// Compiler-only fence for SAME-WAVE LDS exchange: CDNA DS ops from one wave
// complete in program order, so cross-lane RAW within a wave needs no hardware
// drain — only a compiler reordering barrier. Zero cycles.
#define SOFT_FENCE() do { \
  __builtin_amdgcn_wave_barrier(); \
  asm volatile("" ::: "memory"); \
  __builtin_amdgcn_wave_barrier(); \
} while (0)

__device__ __forceinline__ int sniff_wave(const u32* wu, int lane){
  u32 w = wu[lane];
  u32 e = (w >> 7) & 0xFFu;
  unsigned long long m = __ballot(e >= 0x60u && e <= 0x86u);
  return (__popcll(m) > 37) ? 1 : 0;
}

// ---------------- fused prep (grid=1250) — R18-R20 proven, unchanged ----------------
extern "C" __global__ __launch_bounds__(256)
void k_prep_pad(const void* __restrict__ We, const void* __restrict__ Wu,
                const void* __restrict__ U3, const void* __restrict__ U2, const void* __restrict__ U1,
                const void* __restrict__ w1, const void* __restrict__ w2,
                const void* __restrict__ w3, const void* __restrict__ w4,
                const void* __restrict__ pos, const int* __restrict__ eidx,
                float* __restrict__ Hws, float* __restrict__ U3ws,
                float* __restrict__ U2ws, float* __restrict__ U1ws,
                u16* __restrict__ wbws, float4* __restrict__ posf,
                int* __restrict__ cur, u16* __restrict__ el16)
{
  int tid = threadIdx.x;
  int b = blockIdx.x;
  int bf = sniff_wave((const u32*)Wu, tid & 63);

  // fused padded scatter: one edge per thread (1250*256 = NE)
  {
    int e = b*256 + tid;
    int r = eidx[NE + e];
    int s = eidx[e];
    int slot = atomicAdd(&cur[r], 1);
    if (slot < 64) el16[(r << 6) + slot] = (u16)s;
  }

  if (b == 0){
    for (int t = tid; t < 36; t += 256) U1ws[t] = ldf(U1, t, bf);
    for (int t = tid; t < 45; t += 256){
      int j = 0, rem = t;
      for (;;){ int cnt = 9 - j; if (rem < cnt) break; rem -= cnt; ++j; }
      int k = j + rem;
      for (int p = 0; p < 4; ++p){
        float v = ldf(U2, (j*9 + k)*4 + p, bf);
        if (k > j) v += ldf(U2, (k*9 + j)*4 + p, bf);
        U2ws[t*4 + p] = v;
      }
    }
    for (int t = tid; t < 165; t += 256){
      int i = 0, rem = t;
      for (;;){ int m = 9 - i; int cnt = m*(m+1)/2; if (rem < cnt) break; rem -= cnt; ++i; }
      int j = i;
      for (;;){ int cnt = 9 - j; if (rem < cnt) break; rem -= cnt; ++j; }
      int k = j + rem;
      int pm[6][3] = {{i,j,k},{i,k,j},{j,i,k},{j,k,i},{k,i,j},{k,j,i}};
      float acc[4] = {0,0,0,0};
      for (int m = 0; m < 6; ++m){
        bool dup = false;
        for (int mm = 0; mm < m; ++mm)
          if (pm[mm][0]==pm[m][0] && pm[mm][1]==pm[m][1] && pm[mm][2]==pm[m][2]) dup = true;
        if (!dup){
          int base = ((pm[m][0]*9 + pm[m][1])*9 + pm[m][2])*4;
          for (int p = 0; p < 4; ++p) acc[p] += ldf(U3, base + p, bf);
        }
      }
      for (int p = 0; p < 4; ++p) U3ws[t*4 + p] = acc[p];
    }
  } else if (b <= 88){
    // B-frag pack (16x16x32): lane L holds B[k=(L>>4)*8+j][n=L&15]
    int idx = (b - 1)*256 + tid;
    int f = idx >> 9;
    int L = (idx >> 3) & 63;
    int j = idx & 7;
    int kl = ((L >> 4) << 3) + j;
    int n16 = L & 15;
    float v;
    if (f < 4){
      v = (kl < 8) ? ldf(w1, kl*64 + (f*16 + n16), bf) : 0.f;
    } else if (f < 12){
      int g = f - 4; int t = g >> 1, q = g & 1;
      v = ldf(w2, (q*32 + kl)*64 + (t*16 + n16), bf);
    } else if (f < 20){
      int g = f - 12; int t = g >> 1, q = g & 1;
      v = ldf(w3, (q*32 + kl)*64 + (t*16 + n16), bf);
    } else {
      int g = f - 20; int lt = g >> 1, q = g & 1;
      int l = lt >> 2, ct = lt & 3;
      v = ldf(w4, (q*32 + kl)*192 + (l*64 + ct*16 + n16), bf);
    }
    wbws[idx] = f2bf(v);
  } else if (b <= 167){
    int i = (b - 89)*256 + tid;
    if (i < NN){
      float4 v;
      v.x = ldf(pos, 3*i+0, bf); v.y = ldf(pos, 3*i+1, bf); v.z = ldf(pos, 3*i+2, bf); v.w = 0.f;
      posf[i] = v;
    }
  } else if (b <= 177){
    int z = b - 168;
    int c = tid;
    if (c < 64){
      float s = 0.f;
      for (int k = 0; k < 64; ++k) s += ldf(We, z*64 + k, bf) * ldf(Wu, k*64 + c, bf);
      Hws[z*64 + c] = s * 0.0395284708f;   // 1/sqrt(Z*C)
    }
  }
}

// ---------------- edge geometry ----------------
__device__ __forceinline__ void edge_geom(float4 pr, float4 ps, float* ef, float* Y)
{
  float vx = pr.x - ps.x, vy = pr.y - ps.y, vz = pr.z - ps.z;
  float r2 = vx*vx + vy*vy + vz*vz + 1e-12f;
  float rinv = rsqrtf(r2);
  float r = r2 * rinv;
  float ux = vx*rinv, uy = vy*rinv, uz = vz*rinv;
  const float s3 = 1.7320508076f, s5 = 2.2360679775f, s15 = 3.8729833462f;
  Y[0] = 1.0f;
  Y[1] = s3*ux; Y[2] = s3*uy; Y[3] = s3*uz;
  Y[4] = s15*ux*uy; Y[5] = s15*uy*uz;
  Y[6] = 0.5f*s5*(3.0f*uz*uz - 1.0f);
  Y[7] = s15*ux*uz;
  Y[8] = 0.5f*s15*(ux*ux - uy*uy);
  float u = r * 0.2f; u = fminf(u, 1.0f);
  float u2 = u*u, u4 = u2*u2, u6 = u4*u2, u7 = u6*u, u8 = u7*u;
  float fc = 1.0f - 28.0f*u6 + 48.0f*u7 - 21.0f*u8;
  float c0 = 0.63245553203f * fc * rinv;
  float w = 0.62831853072f * r;
  #pragma unroll
  for (int k = 0; k < 8; ++k) ef[k] = c0 * __sinf(w * (float)(k + 1));
}

// ---------------- main: MFMA edge-tile MLP ----------------
// R26 (resubmit after broker timeout): R25 core (swizzled act, packed
// contraction) + amortization:
//  1. 8 nodes/block (2 nodes/wave sequential, grid 2500): prologue (wb/Hs stage
//     + barrier + w-frag hoists) paid half as often; wb L2 refetch halves.
//  2. uint4 staging (b128 load + ds_write_b128): 51 -> 13 issue ops/thread.
//  3. f32x4 contraction accumulators (same v_pk_fma codegen, fewer temps —
//     targets R25's extra 120MB scratch WRITE).
// Regime (R20-R25 A/Bs): latency-bound at 3 waves/SIMD; total regs (VGPR 84 +
// AGPR ~48) > 128 pins occupancy; VALU-count cuts don't move dur (R25).
extern "C" __global__ __launch_bounds__(256, 3)
void k_main(const int* __restrict__ atom,
            const void* __restrict__ Wu,
            const void* __restrict__ Wc3, const void* __restrict__ Wc2, const void* __restrict__ Wc1,
            const void* __restrict__ Woutg,
            const float* __restrict__ Hws, const float* __restrict__ U3ws,
            const float* __restrict__ U2ws, const float* __restrict__ U1ws,
            const float4* __restrict__ posf,
            const int* __restrict__ deg, const u16* __restrict__ el16,
            const u16* __restrict__ wbws, void* __restrict__ outp)
{
  __shared__ __align__(16) u16   wb[12288];         // 24 w4 B-frags, 24576 B
  __shared__ __align__(16) float Hs[10][64];        // 2560 B
  __shared__ __align__(16) u16   efb[4][64][8];     // 4096 B
  __shared__ __align__(16) u16   zb64[4][64];       // 512 B
  __shared__ __align__(16) u16   act[4][1024];      // 8192 B  swizzled [16][64]
  __shared__ __align__(16) u16   Yc[4][64][9];      // 4608 B  compact Y
  __shared__ __align__(16) u16   pfrag[4][4][32][8];// 8192 B  P A-frags (k<16 half)
  // total 52,736 B; 3 blocks/CU (reg-bound anyway)

  int tid = threadIdx.x;
  int wv = tid >> 6;
  int lane = tid & 63;
  int bf = sniff_wave((const u32*)Wu, lane);

  // stage w4 frags (orig frag 20..43 -> uint4 offset 1280) as b128 copies
  for (int t = tid; t < 1536; t += 256)
    ((uint4*)wb)[t] = ((const uint4*)wbws)[1280 + t];
  if (tid < 160) ((float4*)Hs)[tid] = ((const float4*)Hws)[tid];
  __syncthreads();                       // cross-wave: wb/Hs shared

  int c0 = lane & 15;
  int qd = lane >> 4;

  u16* A = &act[wv][0];
  int swr = qd << 4;            // write swizzle: row = qd*4+r -> row>>2 == qd
  int srd = (c0 >> 2) << 4;     // read swizzle:  row = c0

  // hoisted w1/w2/w3 B-frags (registers; loop-invariant across both nodes)
  bf16x8 w1p[4], w2p[8], w3p[8];
  #pragma unroll
  for (int t = 0; t < 4; ++t) w1p[t] = *(const bf16x8*)&wbws[t*512 + lane*8];
  #pragma unroll
  for (int g = 0; g < 8; ++g) w2p[g] = *(const bf16x8*)&wbws[(4+g)*512 + lane*8];
  #pragma unroll
  for (int g = 0; g < 8; ++g) w3p[g] = *(const bf16x8*)&wbws[(12+g)*512 + lane*8];

  int lmap = (c0 == 0) ? 0 : (c0 < 4) ? 1 : 2;
  u32 msk0 = (lmap == 0) ? 0xFFFFFFFFu : 0u;
  u32 msk1 = (lmap == 1) ? 0xFFFFFFFFu : 0u;
  u32 msk2 = (lmap == 2) ? 0xFFFFFFFFu : 0u;

  const f32x4 zero4 = {0.f, 0.f, 0.f, 0.f};
  int prow = ((qd >> 1) << 4) + c0;
  int pcol = (qd & 1) << 2;

  #pragma unroll 1
  for (int inode = 0; inode < 2; ++inode){
    int n = blockIdx.x * 8 + inode * 4 + wv;
    int cnt = min(deg[n], 64);
    float4 pr = posf[n];

    f32x4 XD[4];
    #pragma unroll
    for (int t = 0; t < 4; ++t) XD[t] = zero4;
    int ntile = (cnt + 15) >> 4;

    // ---- gather + geometry (single 64-edge batch; cnt <= 64) ----
    {
      bool valid = lane < cnt;
      int sid = valid ? (int)el16[(n << 6) + lane] : n;
      float4 ps = posf[sid];
      int z = valid ? atom[sid] : 0;
      float ef[8], Y[9];
      edge_geom(pr, ps, ef, Y);
      if (!valid){
        #pragma unroll
        for (int k = 0; k < 8; ++k) ef[k] = 0.f;
        #pragma unroll
        for (int m = 0; m < 9; ++m) Y[m] = 0.f;
      }
      uint4 pk;
      pk.x = pk2bf(ef[0], ef[1]);
      pk.y = pk2bf(ef[2], ef[3]);
      pk.z = pk2bf(ef[4], ef[5]);
      pk.w = pk2bf(ef[6], ef[7]);
      *(uint4*)&efb[wv][lane][0] = pk;
      #pragma unroll
      for (int m = 0; m < 9; ++m) Yc[wv][lane][m] = f2bf(Y[m]);
      zb64[wv][lane] = (u16)z;
    }
    SOFT_FENCE();

    #pragma unroll 1
    for (int t = 0; t < ntile; ++t){
      f32x4 dd[4];

      // ---- L1 ----
      bf16x8 aF = {0,0,0,0,0,0,0,0};
      if (lane < 16) aF = *(const bf16x8*)&efb[wv][t*16 + lane][0];
      #pragma unroll
      for (int t2 = 0; t2 < 4; ++t2) dd[t2] = mfma16(aF, w1p[t2], zero4);
      #pragma unroll
      for (int t2 = 0; t2 < 4; ++t2)
        #pragma unroll
        for (int r = 0; r < 4; ++r)
          A[(((qd*4 + r) << 6) + c0 + (t2 << 4)) ^ swr] = f2bfa(silu_f(dd[t2][r]));
      SOFT_FENCE();

      // ---- L2 ----
      bf16x8 a0 = *(const bf16x8*)&A[((c0 << 6) + (qd << 3)) ^ srd];
      bf16x8 a1 = *(const bf16x8*)&A[((c0 << 6) + 32 + (qd << 3)) ^ srd];
      #pragma unroll
      for (int t2 = 0; t2 < 4; ++t2)
        dd[t2] = mfma16(a1, w2p[t2*2+1], mfma16(a0, w2p[t2*2+0], zero4));
      #pragma unroll
      for (int t2 = 0; t2 < 4; ++t2)
        #pragma unroll
        for (int r = 0; r < 4; ++r)
          A[(((qd*4 + r) << 6) + c0 + (t2 << 4)) ^ swr] = f2bfa(silu_f(dd[t2][r]));
      SOFT_FENCE();

      // ---- L3 (w3 in registers) ----
      a0 = *(const bf16x8*)&A[((c0 << 6) + (qd << 3)) ^ srd];
      a1 = *(const bf16x8*)&A[((c0 << 6) + 32 + (qd << 3)) ^ srd];
      #pragma unroll
      for (int t2 = 0; t2 < 4; ++t2)
        dd[t2] = mfma16(a1, w3p[t2*2+1], mfma16(a0, w3p[t2*2+0], zero4));
      #pragma unroll
      for (int t2 = 0; t2 < 4; ++t2)
        #pragma unroll
        for (int r = 0; r < 4; ++r)
          A[(((qd*4 + r) << 6) + c0 + (t2 << 4)) ^ swr] = f2bfa(silu_f(dd[t2][r]));
      SOFT_FENCE();

      // ---- L4 + X-MFMA ----
      a0 = *(const bf16x8*)&A[((c0 << 6) + (qd << 3)) ^ srd];
      a1 = *(const bf16x8*)&A[((c0 << 6) + 32 + (qd << 3)) ^ srd];

      // rebuild Y B-frag in registers: elem j = Y[(lane>>4)*8+j][c0]
      u32 yd0 = 0, yd1 = 0, yd2 = 0, yd3 = 0;
      if (lane < 32 && c0 < 9){
        const u16* yr = &Yc[wv][t*16 + ((lane >> 4) << 3)][0];
        yd0 = (u32)yr[0*9 + c0] | ((u32)yr[1*9 + c0] << 16);
        yd1 = (u32)yr[2*9 + c0] | ((u32)yr[3*9 + c0] << 16);
        yd2 = (u32)yr[4*9 + c0] | ((u32)yr[5*9 + c0] << 16);
        yd3 = (u32)yr[6*9 + c0] | ((u32)yr[7*9 + c0] << 16);
      }
      bf16x8 B0, B1, B2;
      { uint4 t0 = {yd0 & msk0, yd1 & msk0, yd2 & msk0, yd3 & msk0};
        uint4 t1 = {yd0 & msk1, yd1 & msk1, yd2 & msk1, yd3 & msk1};
        uint4 t2 = {yd0 & msk2, yd1 & msk2, yd2 & msk2, yd3 & msk2};
        B0 = *(bf16x8*)&t0; B1 = *(bf16x8*)&t1; B2 = *(bf16x8*)&t2; }

      float hv[4][4];
      #pragma unroll
      for (int r = 0; r < 4; ++r){
        int z_e = (int)zb64[wv][t*16 + qd*4 + r];
        #pragma unroll
        for (int ct = 0; ct < 4; ++ct) hv[r][ct] = Hs[z_e][ct*16 + c0];
      }
      #pragma unroll
      for (int l = 0; l < 3; ++l){
        #pragma unroll
        for (int ct = 0; ct < 4; ++ct){
          int f = (l*4 + ct)*2;
          bf16x8 b0 = *(const bf16x8*)&wb[f*512 + lane*8];
          bf16x8 b1 = *(const bf16x8*)&wb[(f+1)*512 + lane*8];
          dd[ct] = mfma16(a1, b1, mfma16(a0, b0, zero4));
        }
        #pragma unroll
        for (int ct = 0; ct < 4; ++ct){
          uint2 pk2;
          pk2.x = pk2bf(hv[0][ct] * dd[ct][0], hv[1][ct] * dd[ct][1]);
          pk2.y = pk2bf(hv[2][ct] * dd[ct][2], hv[3][ct] * dd[ct][3]);
          *(uint2*)&pfrag[wv][ct][prow][pcol] = pk2;
        }
        SOFT_FENCE();
        bf16x8 Bl = (l == 0) ? B0 : (l == 1) ? B1 : B2;
        #pragma unroll
        for (int ct = 0; ct < 4; ++ct){
          bf16x8 aP = {0,0,0,0,0,0,0,0};
          if (lane < 32) aP = *(const bf16x8*)&pfrag[wv][ct][lane][0];
          XD[ct] = mfma16(aP, Bl, XD[ct]);
        }
        SOFT_FENCE();
      }
    }

    // ---- redistribute X: D-frags -> Xf8 (act slice) + X8f (efb slice) ----
    float* Xf8 = (float*)A;                 // [64][8] f32 = 2048 B
    float* X8f = (float*)&efb[wv][0][0];    // [64] f32 = 256 B
    SOFT_FENCE();
    #pragma unroll
    for (int ct = 0; ct < 4; ++ct)
      #pragma unroll
      for (int r = 0; r < 4; ++r){
        int c = ct*16 + qd*4 + r;
        if (c0 < 8)       Xf8[c*8 + c0] = XD[ct][r];
        else if (c0 == 8) X8f[c]        = XD[ct][r];
      }
    SOFT_FENCE();
    float X[9];
    {
      const float4* xr = (const float4*)&Xf8[lane*8];
      float4 xa = xr[0], xb = xr[1];
      X[0]=xa.x; X[1]=xa.y; X[2]=xa.z; X[3]=xa.w;
      X[4]=xb.x; X[5]=xb.y; X[6]=xb.z; X[7]=xb.w;
      X[8]=X8f[lane];
    }
    #pragma unroll
    for (int m = 0; m < 9; ++m) X[m] *= 0.0625f;   // / AVG

    // ---- contraction (f32x4 accumulators -> v_pk_fma_f32 pairs) ----
    const f32x4* U1g = (const f32x4*)U1ws;
    const f32x4* U2g = (const f32x4*)U2ws;
    const f32x4* U3g = (const f32x4*)U3ws;
    f32x4 s1 = zero4, s2 = zero4, s3 = zero4;
    #pragma unroll
    for (int j = 0; j < 9; ++j) s1 += U1g[j] * X[j];
    {
      int t2i = 0;
      #pragma unroll
      for (int j = 0; j < 9; ++j)
        #pragma unroll
        for (int k = j; k < 9; ++k){
          float m = X[j]*X[k];
          s2 += U2g[t2i] * m; ++t2i;
        }
    }
    {
      int t3i = 0;
      #pragma unroll
      for (int i = 0; i < 9; ++i)
        #pragma unroll
        for (int j = i; j < 9; ++j){
          float mij = X[i]*X[j];
          #pragma unroll
          for (int k = j; k < 9; ++k){
            s3 += U3g[t3i] * (mij*X[k]); ++t3i;
          }
        }
    }

    int zn = atom[n];
    float outval = 0.f;
    #pragma unroll
    for (int p = 0; p < 4; ++p){
      int b = (zn*4 + p)*64 + lane;
      outval += ldf(Wc1, b, bf)*s1[p] + ldf(Wc2, b, bf)*s2[p] + ldf(Wc3, b, bf)*s3[p];
    }

    // ---- final matmul (xchg reuses act slice after Xf8 consumed) ----
    float* xchg = (float*)A;
    SOFT_FENCE();
    xchg[lane] = outval;
    SOFT_FENCE();
    float acc = 0.f;
    const float4* pb = (const float4*)xchg;
    if (bf){
      const u16* wg = (const u16*)Woutg;
      #pragma unroll
      for (int cb = 0; cb < 16; ++cb){
        float4 p = pb[cb];
        acc += p.x*bf2f(wg[(4*cb+0)*64 + lane]) + p.y*bf2f(wg[(4*cb+1)*64 + lane])
             + p.z*bf2f(wg[(4*cb+2)*64 + lane]) + p.w*bf2f(wg[(4*cb+3)*64 + lane]);
      }
    } else {
      const float* wg = (const float*)Woutg;
      #pragma unroll
      for (int cb = 0; cb < 16; ++cb){
        float4 p = pb[cb];
        acc += p.x*wg[(4*cb+0)*64 + lane] + p.y*wg[(4*cb+1)*64 + lane]
             + p.z*wg[(4*cb+2)*64 + lane] + p.w*wg[(4*cb+3)*64 + lane];
      }
    }
    acc *= 0.125f;
    if (bf) ((u16*)outp)[n*64 + lane] = f2bf(acc);
    else    ((float*)outp)[n*64 + lane] = acc;
    SOFT_FENCE();   // xchg/act reused by next node
  }
}

// ---------------- host ----------------
extern "C" void kernel_launch(void* const* d_in, const int* in_sizes, int n_in,
                              void* d_out, int out_size, void* d_ws, size_t ws_size,
                              hipStream_t stream)
{
  const void* pos  = d_in[0];
  const int* atom  = (const int*)d_in[1];
  const int* eidx  = (const int*)d_in[2];
  const void* We   = d_in[3];
  const void* Wu   = d_in[4];
  const void* w1g  = d_in[5];
  const void* w2g  = d_in[6];
  const void* w3g  = d_in[7];
  const void* w4g  = d_in[8];
  const void* U3   = d_in[9];
  const void* U2   = d_in[10];
  const void* U1   = d_in[11];
  const void* Wc3  = d_in[12];
  const void* Wc2  = d_in[13];
  const void* Wc1  = d_in[14];
  const void* Wout = d_in[15];

  char* ws = (char*)d_ws;
  float*  Hws   = (float*)(ws + WP_H);
  float*  U1ws  = (float*)(ws + WP_U1);
  float*  U2ws  = (float*)(ws + WP_U2);
  float*  U3ws  = (float*)(ws + WP_U3);
  int*    cur   = (int*)(ws + WP_CUR);
  float4* posf  = (float4*)(ws + WP_POSF);
  u16*    wbws  = (u16*)(ws + WP_WB);
  u16*    el16  = (u16*)(ws + WP_EL16);

  (void)hipMemsetAsync(ws + WP_CUR, 0, 80000, stream);
  k_prep_pad<<<1250, 256, 0, stream>>>(We, Wu, U3, U2, U1, w1g, w2g, w3g, w4g, pos, eidx,
                                       Hws, U3ws, U2ws, U1ws, wbws, posf, cur, el16);
  k_main<<<2500, 256, 0, stream>>>(atom, Wu, Wc3, Wc2, Wc1, Wout,
                                   Hws, U3ws, U2ws, U1ws, posf,
                                   cur, el16, wbws, d_out);
}

// Round 9
// 283.082 us; speedup vs baseline: 2.1064x; 2.1064x over previous
//
#include <hip/hip_runtime.h>
#include <hip/hip_bf16.h>

typedef unsigned short u16;
typedef unsigned int u32;
typedef __attribute__((ext_vector_type(8))) short bf16x8;
typedef __attribute__((ext_vector_type(4))) float f32x4;

#define NN 20000
#define NE 320000

// ---------------- workspace layout (padded CSR; ws_size >= 3,012,224 proven) ----------------
#define WP_H     256       // 640 f32
#define WP_U1    3072      // 36 f32
#define WP_U2    3328      // 180 f32
#define WP_U3    4096      // 660 f32
#define WP_CUR   7168      // 20000 i32 (doubles as deg for k_main)
#define WP_POSF  87168     // 20000 float4
#define WP_WB    407168    // 22528 u16
#define WP_EL16  452224    // 20000*64 u16

__device__ __forceinline__ float bf2f(u16 u){ return __uint_as_float(((u32)u) << 16); }
__device__ __forceinline__ u16 f2bf(float f){
  u32 u = __float_as_uint(f);
  u32 r = (u + 0x7fffu + ((u >> 16) & 1u)) >> 16;
  return (u16)r;
}
__device__ __forceinline__ u16 f2bfa(float f){
  return (u16)((__float_as_uint(f) + 0x8000u) >> 16);
}
__device__ __forceinline__ u32 pk2bf(float a, float b){
  __hip_bfloat162 h = __float22bfloat162_rn(make_float2(a, b));
  return *(u32*)&h;
}
__device__ __forceinline__ float silu_f(float v){
  return v * __builtin_amdgcn_rcpf(1.0f + __expf(-v));
}
__device__ __forceinline__ float ldf(const void* p, int i, int bf){
  return bf ? bf2f(((const u16*)p)[i]) : ((const float*)p)[i];
}
__device__ __forceinline__ f32x4 mfma16(bf16x8 a, bf16x8 b, f32x4 c){
  return __builtin_amdgcn_mfma_f32_16x16x32_bf16(a, b, c, 0, 0, 0);
}

// Compiler-only fence for SAME-WAVE LDS exchange: CDNA DS ops from one wave
// complete in program order, so cross-lane RAW within a wave needs no hardware
// drain — only a compiler reordering barrier. Zero cycles.
#define SOFT_FENCE() do { \
  __builtin_amdgcn_wave_barrier(); \
  asm volatile("" ::: "memory"); \
  __builtin_amdgcn_wave_barrier(); \
} while (0)

__device__ __forceinline__ int sniff_wave(const u32* wu, int lane){
  u32 w = wu[lane];
  u32 e = (w >> 7) & 0xFFu;
  unsigned long long m = __ballot(e >= 0x60u && e <= 0x86u);
  return (__popcll(m) > 37) ? 1 : 0;
}

// ---------------- fused prep (grid=1250) — R18-R20 proven, unchanged ----------------
extern "C" __global__ __launch_bounds__(256)
void k_prep_pad(const void* __restrict__ We, const void* __restrict__ Wu,
                const void* __restrict__ U3, const void* __restrict__ U2, const void* __restrict__ U1,
                const void* __restrict__ w1, const void* __restrict__ w2,
                const void* __restrict__ w3, const void* __restrict__ w4,
                const void* __restrict__ pos, const int* __restrict__ eidx,
                float* __restrict__ Hws, float* __restrict__ U3ws,
                float* __restrict__ U2ws, float* __restrict__ U1ws,
                u16* __restrict__ wbws, float4* __restrict__ posf,
                int* __restrict__ cur, u16* __restrict__ el16)
{
  int tid = threadIdx.x;
  int b = blockIdx.x;
  int bf = sniff_wave((const u32*)Wu, tid & 63);

  // fused padded scatter: one edge per thread (1250*256 = NE)
  {
    int e = b*256 + tid;
    int r = eidx[NE + e];
    int s = eidx[e];
    int slot = atomicAdd(&cur[r], 1);
    if (slot < 64) el16[(r << 6) + slot] = (u16)s;
  }

  if (b == 0){
    for (int t = tid; t < 36; t += 256) U1ws[t] = ldf(U1, t, bf);
    for (int t = tid; t < 45; t += 256){
      int j = 0, rem = t;
      for (;;){ int cnt = 9 - j; if (rem < cnt) break; rem -= cnt; ++j; }
      int k = j + rem;
      for (int p = 0; p < 4; ++p){
        float v = ldf(U2, (j*9 + k)*4 + p, bf);
        if (k > j) v += ldf(U2, (k*9 + j)*4 + p, bf);
        U2ws[t*4 + p] = v;
      }
    }
    for (int t = tid; t < 165; t += 256){
      int i = 0, rem = t;
      for (;;){ int m = 9 - i; int cnt = m*(m+1)/2; if (rem < cnt) break; rem -= cnt; ++i; }
      int j = i;
      for (;;){ int cnt = 9 - j; if (rem < cnt) break; rem -= cnt; ++j; }
      int k = j + rem;
      int pm[6][3] = {{i,j,k},{i,k,j},{j,i,k},{j,k,i},{k,i,j},{k,j,i}};
      float acc[4] = {0,0,0,0};
      for (int m = 0; m < 6; ++m){
        bool dup = false;
        for (int mm = 0; mm < m; ++mm)
          if (pm[mm][0]==pm[m][0] && pm[mm][1]==pm[m][1] && pm[mm][2]==pm[m][2]) dup = true;
        if (!dup){
          int base = ((pm[m][0]*9 + pm[m][1])*9 + pm[m][2])*4;
          for (int p = 0; p < 4; ++p) acc[p] += ldf(U3, base + p, bf);
        }
      }
      for (int p = 0; p < 4; ++p) U3ws[t*4 + p] = acc[p];
    }
  } else if (b <= 88){
    // B-frag pack (16x16x32): lane L holds B[k=(L>>4)*8+j][n=L&15]
    int idx = (b - 1)*256 + tid;
    int f = idx >> 9;
    int L = (idx >> 3) & 63;
    int j = idx & 7;
    int kl = ((L >> 4) << 3) + j;
    int n16 = L & 15;
    float v;
    if (f < 4){
      v = (kl < 8) ? ldf(w1, kl*64 + (f*16 + n16), bf) : 0.f;
    } else if (f < 12){
      int g = f - 4; int t = g >> 1, q = g & 1;
      v = ldf(w2, (q*32 + kl)*64 + (t*16 + n16), bf);
    } else if (f < 20){
      int g = f - 12; int t = g >> 1, q = g & 1;
      v = ldf(w3, (q*32 + kl)*64 + (t*16 + n16), bf);
    } else {
      int g = f - 20; int lt = g >> 1, q = g & 1;
      int l = lt >> 2, ct = lt & 3;
      v = ldf(w4, (q*32 + kl)*192 + (l*64 + ct*16 + n16), bf);
    }
    wbws[idx] = f2bf(v);
  } else if (b <= 167){
    int i = (b - 89)*256 + tid;
    if (i < NN){
      float4 v;
      v.x = ldf(pos, 3*i+0, bf); v.y = ldf(pos, 3*i+1, bf); v.z = ldf(pos, 3*i+2, bf); v.w = 0.f;
      posf[i] = v;
    }
  } else if (b <= 177){
    int z = b - 168;
    int c = tid;
    if (c < 64){
      float s = 0.f;
      for (int k = 0; k < 64; ++k) s += ldf(We, z*64 + k, bf) * ldf(Wu, k*64 + c, bf);
      Hws[z*64 + c] = s * 0.0395284708f;   // 1/sqrt(Z*C)
    }
  }
}

// ---------------- edge geometry ----------------
__device__ __forceinline__ void edge_geom(float4 pr, float4 ps, float* ef, float* Y)
{
  float vx = pr.x - ps.x, vy = pr.y - ps.y, vz = pr.z - ps.z;
  float r2 = vx*vx + vy*vy + vz*vz + 1e-12f;
  float rinv = rsqrtf(r2);
  float r = r2 * rinv;
  float ux = vx*rinv, uy = vy*rinv, uz = vz*rinv;
  const float s3 = 1.7320508076f, s5 = 2.2360679775f, s15 = 3.8729833462f;
  Y[0] = 1.0f;
  Y[1] = s3*ux; Y[2] = s3*uy; Y[3] = s3*uz;
  Y[4] = s15*ux*uy; Y[5] = s15*uy*uz;
  Y[6] = 0.5f*s5*(3.0f*uz*uz - 1.0f);
  Y[7] = s15*ux*uz;
  Y[8] = 0.5f*s15*(ux*ux - uy*uy);
  float u = r * 0.2f; u = fminf(u, 1.0f);
  float u2 = u*u, u4 = u2*u2, u6 = u4*u2, u7 = u6*u, u8 = u7*u;
  float fc = 1.0f - 28.0f*u6 + 48.0f*u7 - 21.0f*u8;
  float c0 = 0.63245553203f * fc * rinv;
  float w = 0.62831853072f * r;
  #pragma unroll
  for (int k = 0; k < 8; ++k) ef[k] = c0 * __sinf(w * (float)(k + 1));
}

// ---------------- main: MFMA edge-tile MLP ----------------
// R27 (second resubmit after infra failures): R25 base (best verified: 196.0 us)
// + three isolated low-risk changes:
//  1. f32x4-accumulator contraction (targets R25's 160MB spill WRITE).
//  2. gather chain (deg->el16->posf[sid]->atom[sid], ~700cy dependent L2
//     latency) issued at kernel TOP, overlapping wb staging + weight hoists +
//     barrier. Per-wave LDS writes (efb/Yc/zb64) are disjoint from wb/Hs;
//     __syncthreads subsumes the old SOFT_FENCE.
//  3. b128 staging for wb/Hs.
// Proven dead ends (do NOT revisit): occupancy >3 blocks (R21/R23/R24 spills),
// VALU-count cuts (R25: -7pts VALUBusy, -1.7us), node batching (R26: weights
// live across epilogue -> 64KB/wave scratch, 2.5x regression).
extern "C" __global__ __launch_bounds__(256, 3)
void k_main(const int* __restrict__ atom,
            const void* __restrict__ Wu,
            const void* __restrict__ Wc3, const void* __restrict__ Wc2, const void* __restrict__ Wc1,
            const void* __restrict__ Woutg,
            const float* __restrict__ Hws, const float* __restrict__ U3ws,
            const float* __restrict__ U2ws, const float* __restrict__ U1ws,
            const float4* __restrict__ posf,
            const int* __restrict__ deg, const u16* __restrict__ el16,
            const u16* __restrict__ wbws, void* __restrict__ outp)
{
  __shared__ __align__(16) u16   wb[12288];         // 24 w4 B-frags, 24576 B
  __shared__ __align__(16) float Hs[10][64];        // 2560 B
  __shared__ __align__(16) u16   efb[4][64][8];     // 4096 B
  __shared__ __align__(16) u16   zb64[4][64];       // 512 B
  __shared__ __align__(16) u16   act[4][1024];      // 8192 B  swizzled [16][64]
  __shared__ __align__(16) u16   Yc[4][64][9];      // 4608 B  compact Y
  __shared__ __align__(16) u16   pfrag[4][4][32][8];// 8192 B  P A-frags (k<16 half)
  // total 52,736 B; 3 blocks/CU (reg-bound anyway)

  int tid = threadIdx.x;
  int wv = tid >> 6;
  int lane = tid & 63;
  int bf = sniff_wave((const u32*)Wu, lane);

  int c0 = lane & 15;
  int qd = lane >> 4;
  int n = blockIdx.x * 4 + wv;

  // ---- gather chain issued ASAP (latency hides under staging + hoists) ----
  int cnt = min(deg[n], 64);
  int el  = (int)el16[(n << 6) + lane];   // padded row, always safe
  float4 pr = posf[n];

  // stage w4 frags (orig frag 20..43 -> uint4 offset 1280) as b128 copies
  for (int t = tid; t < 1536; t += 256)
    ((uint4*)wb)[t] = ((const uint4*)wbws)[1280 + t];
  if (tid < 160) ((float4*)Hs)[tid] = ((const float4*)Hws)[tid];

  bool valid = lane < cnt;
  int sid = valid ? el : n;
  float4 ps = posf[sid];
  int z = valid ? atom[sid] : 0;

  // hoisted w1/w2/w3 B-frags (registers; loop-invariant)
  bf16x8 w1p[4], w2p[8], w3p[8];
  #pragma unroll
  for (int t = 0; t < 4; ++t) w1p[t] = *(const bf16x8*)&wbws[t*512 + lane*8];
  #pragma unroll
  for (int g = 0; g < 8; ++g) w2p[g] = *(const bf16x8*)&wbws[(4+g)*512 + lane*8];
  #pragma unroll
  for (int g = 0; g < 8; ++g) w3p[g] = *(const bf16x8*)&wbws[(12+g)*512 + lane*8];

  // ---- geometry + per-wave LDS writes (efb/Yc/zb64 disjoint from wb/Hs) ----
  {
    float ef[8], Y[9];
    edge_geom(pr, ps, ef, Y);
    if (!valid){
      #pragma unroll
      for (int k = 0; k < 8; ++k) ef[k] = 0.f;
      #pragma unroll
      for (int m = 0; m < 9; ++m) Y[m] = 0.f;
    }
    uint4 pk;
    pk.x = pk2bf(ef[0], ef[1]);
    pk.y = pk2bf(ef[2], ef[3]);
    pk.z = pk2bf(ef[4], ef[5]);
    pk.w = pk2bf(ef[6], ef[7]);
    *(uint4*)&efb[wv][lane][0] = pk;
    #pragma unroll
    for (int m = 0; m < 9; ++m) Yc[wv][lane][m] = f2bf(Y[m]);
    zb64[wv][lane] = (u16)z;
  }
  __syncthreads();   // covers wb/Hs staging AND the per-wave efb/Yc/zb64 writes

  u16* A = &act[wv][0];
  int swr = qd << 4;            // write swizzle: row = qd*4+r -> row>>2 == qd
  int srd = (c0 >> 2) << 4;     // read swizzle:  row = c0

  int lmap = (c0 == 0) ? 0 : (c0 < 4) ? 1 : 2;
  u32 msk0 = (lmap == 0) ? 0xFFFFFFFFu : 0u;
  u32 msk1 = (lmap == 1) ? 0xFFFFFFFFu : 0u;
  u32 msk2 = (lmap == 2) ? 0xFFFFFFFFu : 0u;

  const f32x4 zero4 = {0.f, 0.f, 0.f, 0.f};
  f32x4 XD[4];
  #pragma unroll
  for (int t = 0; t < 4; ++t) XD[t] = zero4;

  int prow = ((qd >> 1) << 4) + c0;
  int pcol = (qd & 1) << 2;
  int ntile = (cnt + 15) >> 4;

  #pragma unroll 1
  for (int t = 0; t < ntile; ++t){
    f32x4 dd[4];

    // ---- L1 ----
    bf16x8 aF = {0,0,0,0,0,0,0,0};
    if (lane < 16) aF = *(const bf16x8*)&efb[wv][t*16 + lane][0];
    #pragma unroll
    for (int t2 = 0; t2 < 4; ++t2) dd[t2] = mfma16(aF, w1p[t2], zero4);
    #pragma unroll
    for (int t2 = 0; t2 < 4; ++t2)
      #pragma unroll
      for (int r = 0; r < 4; ++r)
        A[(((qd*4 + r) << 6) + c0 + (t2 << 4)) ^ swr] = f2bfa(silu_f(dd[t2][r]));
    SOFT_FENCE();

    // ---- L2 ----
    bf16x8 a0 = *(const bf16x8*)&A[((c0 << 6) + (qd << 3)) ^ srd];
    bf16x8 a1 = *(const bf16x8*)&A[((c0 << 6) + 32 + (qd << 3)) ^ srd];
    #pragma unroll
    for (int t2 = 0; t2 < 4; ++t2)
      dd[t2] = mfma16(a1, w2p[t2*2+1], mfma16(a0, w2p[t2*2+0], zero4));
    #pragma unroll
    for (int t2 = 0; t2 < 4; ++t2)
      #pragma unroll
      for (int r = 0; r < 4; ++r)
        A[(((qd*4 + r) << 6) + c0 + (t2 << 4)) ^ swr] = f2bfa(silu_f(dd[t2][r]));
    SOFT_FENCE();

    // ---- L3 (w3 in registers) ----
    a0 = *(const bf16x8*)&A[((c0 << 6) + (qd << 3)) ^ srd];
    a1 = *(const bf16x8*)&A[((c0 << 6) + 32 + (qd << 3)) ^ srd];
    #pragma unroll
    for (int t2 = 0; t2 < 4; ++t2)
      dd[t2] = mfma16(a1, w3p[t2*2+1], mfma16(a0, w3p[t2*2+0], zero4));
    #pragma unroll
    for (int t2 = 0; t2 < 4; ++t2)
      #pragma unroll
      for (int r = 0; r < 4; ++r)
        A[(((qd*4 + r) << 6) + c0 + (t2 << 4)) ^ swr] = f2bfa(silu_f(dd[t2][r]));
    SOFT_FENCE();

    // ---- L4 + X-MFMA ----
    a0 = *(const bf16x8*)&A[((c0 << 6) + (qd << 3)) ^ srd];
    a1 = *(const bf16x8*)&A[((c0 << 6) + 32 + (qd << 3)) ^ srd];

    // rebuild Y B-frag in registers: elem j = Y[(lane>>4)*8+j][c0]
    u32 yd0 = 0, yd1 = 0, yd2 = 0, yd3 = 0;
    if (lane < 32 && c0 < 9){
      const u16* yr = &Yc[wv][t*16 + ((lane >> 4) << 3)][0];
      yd0 = (u32)yr[0*9 + c0] | ((u32)yr[1*9 + c0] << 16);
      yd1 = (u32)yr[2*9 + c0] | ((u32)yr[3*9 + c0] << 16);
      yd2 = (u32)yr[4*9 + c0] | ((u32)yr[5*9 + c0] << 16);
      yd3 = (u32)yr[6*9 + c0] | ((u32)yr[7*9 + c0] << 16);
    }
    bf16x8 B0, B1, B2;
    { uint4 t0 = {yd0 & msk0, yd1 & msk0, yd2 & msk0, yd3 & msk0};
      uint4 t1 = {yd0 & msk1, yd1 & msk1, yd2 & msk1, yd3 & msk1};
      uint4 t2 = {yd0 & msk2, yd1 & msk2, yd2 & msk2, yd3 & msk2};
      B0 = *(bf16x8*)&t0; B1 = *(bf16x8*)&t1; B2 = *(bf16x8*)&t2; }

    float hv[4][4];
    #pragma unroll
    for (int r = 0; r < 4; ++r){
      int z_e = (int)zb64[wv][t*16 + qd*4 + r];
      #pragma unroll
      for (int ct = 0; ct < 4; ++ct) hv[r][ct] = Hs[z_e][ct*16 + c0];
    }
    #pragma unroll
    for (int l = 0; l < 3; ++l){
      #pragma unroll
      for (int ct = 0; ct < 4; ++ct){
        int f = (l*4 + ct)*2;
        bf16x8 b0 = *(const bf16x8*)&wb[f*512 + lane*8];
        bf16x8 b1 = *(const bf16x8*)&wb[(f+1)*512 + lane*8];
        dd[ct] = mfma16(a1, b1, mfma16(a0, b0, zero4));
      }
      #pragma unroll
      for (int ct = 0; ct < 4; ++ct){
        uint2 pk2;
        pk2.x = pk2bf(hv[0][ct] * dd[ct][0], hv[1][ct] * dd[ct][1]);
        pk2.y = pk2bf(hv[2][ct] * dd[ct][2], hv[3][ct] * dd[ct][3]);
        *(uint2*)&pfrag[wv][ct][prow][pcol] = pk2;
      }
      SOFT_FENCE();
      bf16x8 Bl = (l == 0) ? B0 : (l == 1) ? B1 : B2;
      #pragma unroll
      for (int ct = 0; ct < 4; ++ct){
        bf16x8 aP = {0,0,0,0,0,0,0,0};
        if (lane < 32) aP = *(const bf16x8*)&pfrag[wv][ct][lane][0];
        XD[ct] = mfma16(aP, Bl, XD[ct]);
      }
      SOFT_FENCE();
    }
  }

  // ---- redistribute X: D-frags -> Xf8 (act slice) + X8f (efb slice) ----
  float* Xf8 = (float*)A;                 // [64][8] f32 = 2048 B
  float* X8f = (float*)&efb[wv][0][0];    // [64] f32 = 256 B
  SOFT_FENCE();
  #pragma unroll
  for (int ct = 0; ct < 4; ++ct)
    #pragma unroll
    for (int r = 0; r < 4; ++r){
      int c = ct*16 + qd*4 + r;
      if (c0 < 8)       Xf8[c*8 + c0] = XD[ct][r];
      else if (c0 == 8) X8f[c]        = XD[ct][r];
    }
  SOFT_FENCE();
  float X[9];
  {
    const float4* xr = (const float4*)&Xf8[lane*8];
    float4 xa = xr[0], xb = xr[1];
    X[0]=xa.x; X[1]=xa.y; X[2]=xa.z; X[3]=xa.w;
    X[4]=xb.x; X[5]=xb.y; X[6]=xb.z; X[7]=xb.w;
    X[8]=X8f[lane];
  }
  #pragma unroll
  for (int m = 0; m < 9; ++m) X[m] *= 0.0625f;   // / AVG

  // ---- contraction (f32x4 accumulators -> v_pk_fma_f32 pairs) ----
  const f32x4* U1g = (const f32x4*)U1ws;
  const f32x4* U2g = (const f32x4*)U2ws;
  const f32x4* U3g = (const f32x4*)U3ws;
  f32x4 s1 = zero4, s2 = zero4, s3 = zero4;
  #pragma unroll
  for (int j = 0; j < 9; ++j) s1 += U1g[j] * X[j];
  {
    int t2i = 0;
    #pragma unroll
    for (int j = 0; j < 9; ++j)
      #pragma unroll
      for (int k = j; k < 9; ++k){
        float m = X[j]*X[k];
        s2 += U2g[t2i] * m; ++t2i;
      }
  }
  {
    int t3i = 0;
    #pragma unroll
    for (int i = 0; i < 9; ++i)
      #pragma unroll
      for (int j = i; j < 9; ++j){
        float mij = X[i]*X[j];
        #pragma unroll
        for (int k = j; k < 9; ++k){
          s3 += U3g[t3i] * (mij*X[k]); ++t3i;
        }
      }
  }

  int zn = atom[n];
  float outval = 0.f;
  #pragma unroll
  for (int p = 0; p < 4; ++p){
    int b = (zn*4 + p)*64 + lane;
    outval += ldf(Wc1, b, bf)*s1[p] + ldf(Wc2, b, bf)*s2[p] + ldf(Wc3, b, bf)*s3[p];
  }

  // ---- final matmul (xchg reuses act slice after Xf8 consumed) ----
  float* xchg = (float*)A;
  SOFT_FENCE();
  xchg[lane] = outval;
  SOFT_FENCE();
  float acc = 0.f;
  const float4* pb = (const float4*)xchg;
  if (bf){
    const u16* wg = (const u16*)Woutg;
    #pragma unroll
    for (int cb = 0; cb < 16; ++cb){
      float4 p = pb[cb];
      acc += p.x*bf2f(wg[(4*cb+0)*64 + lane]) + p.y*bf2f(wg[(4*cb+1)*64 + lane])
           + p.z*bf2f(wg[(4*cb+2)*64 + lane]) + p.w*bf2f(wg[(4*cb+3)*64 + lane]);
    }
  } else {
    const float* wg = (const float*)Woutg;
    #pragma unroll
    for (int cb = 0; cb < 16; ++cb){
      float4 p = pb[cb];
      acc += p.x*wg[(4*cb+0)*64 + lane] + p.y*wg[(4*cb+1)*64 + lane]
           + p.z*wg[(4*cb+2)*64 + lane] + p.w*wg[(4*cb+3)*64 + lane];
    }
  }
  acc *= 0.125f;
  if (bf) ((u16*)outp)[n*64 + lane] = f2bf(acc);
  else    ((float*)outp)[n*64 + lane] = acc;
}

// ---------------- host ----------------
extern "C" void kernel_launch(void* const* d_in, const int* in_sizes, int n_in,
                              void* d_out, int out_size, void* d_ws, size_t ws_size,
                              hipStream_t stream)
{
  const void* pos  = d_in[0];
  const int* atom  = (const int*)d_in[1];
  const int* eidx  = (const int*)d_in[2];
  const void* We   = d_in[3];
  const void* Wu   = d_in[4];
  const void* w1g  = d_in[5];
  const void* w2g  = d_in[6];
  const void* w3g  = d_in[7];
  const void* w4g  = d_in[8];
  const void* U3   = d_in[9];
  const void* U2   = d_in[10];
  const void* U1   = d_in[11];
  const void* Wc3  = d_in[12];
  const void* Wc2  = d_in[13];
  const void* Wc1  = d_in[14];
  const void* Wout = d_in[15];

  char* ws = (char*)d_ws;
  float*  Hws   = (float*)(ws + WP_H);
  float*  U1ws  = (float*)(ws + WP_U1);
  float*  U2ws  = (float*)(ws + WP_U2);
  float*  U3ws  = (float*)(ws + WP_U3);
  int*    cur   = (int*)(ws + WP_CUR);
  float4* posf  = (float4*)(ws + WP_POSF);
  u16*    wbws  = (u16*)(ws + WP_WB);
  u16*    el16  = (u16*)(ws + WP_EL16);

  (void)hipMemsetAsync(ws + WP_CUR, 0, 80000, stream);
  k_prep_pad<<<1250, 256, 0, stream>>>(We, Wu, U3, U2, U1, w1g, w2g, w3g, w4g, pos, eidx,
                                       Hws, U3ws, U2ws, U1ws, wbws, posf, cur, el16);
  k_main<<<5000, 256, 0, stream>>>(atom, Wu, Wc3, Wc2, Wc1, Wout,
                                   Hws, U3ws, U2ws, U1ws, posf,
                                   cur, el16, wbws, d_out);
}

// Round 10
// 281.412 us; speedup vs baseline: 2.1189x; 1.0059x over previous
//
#include <hip/hip_runtime.h>
#include <hip/hip_bf16.h>

typedef unsigned short u16;
typedef unsigned int u32;
typedef __attribute__((ext_vector_type(8))) short bf16x8;
typedef __attribute__((ext_vector_type(4))) float f32x4;

#define NN 20000
#define NE 320000

// ---------------- workspace layout (padded CSR; ws_size >= 3,012,224 proven) ----------------
#define WP_H     256       // 640 f32
#define WP_U1    3072      // 36 f32
#define WP_U2    3328      // 180 f32
#define WP_U3    4096      // 660 f32
#define WP_CUR   7168      // 20000 i32 (doubles as deg for k_main)
#define WP_POSF  87168     // 20000 float4
#define WP_WB    407168    // 22528 u16
#define WP_EL16  452224    // 20000*64 u16

__device__ __forceinline__ float bf2f(u16 u){ return __uint_as_float(((u32)u) << 16); }
__device__ __forceinline__ u16 f2bf(float f){
  u32 u = __float_as_uint(f);
  u32 r = (u + 0x7fffu + ((u >> 16) & 1u)) >> 16;
  return (u16)r;
}
__device__ __forceinline__ u16 f2bfa(float f){
  return (u16)((__float_as_uint(f) + 0x8000u) >> 16);
}
__device__ __forceinline__ u32 pk2bf(float a, float b){
  __hip_bfloat162 h = __float22bfloat162_rn(make_float2(a, b));
  return *(u32*)&h;
}
__device__ __forceinline__ float silu_f(float v){
  return v * __builtin_amdgcn_rcpf(1.0f + __expf(-v));
}
__device__ __forceinline__ float ldf(const void* p, int i, int bf){
  return bf ? bf2f(((const u16*)p)[i]) : ((const float*)p)[i];
}
__device__ __forceinline__ f32x4 mfma16(bf16x8 a, bf16x8 b, f32x4 c){
  return __builtin_amdgcn_mfma_f32_16x16x32_bf16(a, b, c, 0, 0, 0);
}

// Compiler-only fence for SAME-WAVE LDS exchange: CDNA DS ops from one wave
// complete in program order, so cross-lane RAW within a wave needs no hardware
// drain — only a compiler reordering barrier. Zero cycles.
#define SOFT_FENCE() do { \
  __builtin_amdgcn_wave_barrier(); \
  asm volatile("" ::: "memory"); \
  __builtin_amdgcn_wave_barrier(); \
} while (0)

__device__ __forceinline__ int sniff_wave(const u32* wu, int lane){
  u32 w = wu[lane];
  u32 e = (w >> 7) & 0xFFu;
  unsigned long long m = __ballot(e >= 0x60u && e <= 0x86u);
  return (__popcll(m) > 37) ? 1 : 0;
}

// ---------------- fused prep (grid=1250) — R18-R20 proven, unchanged ----------------
extern "C" __global__ __launch_bounds__(256)
void k_prep_pad(const void* __restrict__ We, const void* __restrict__ Wu,
                const void* __restrict__ U3, const void* __restrict__ U2, const void* __restrict__ U1,
                const void* __restrict__ w1, const void* __restrict__ w2,
                const void* __restrict__ w3, const void* __restrict__ w4,
                const void* __restrict__ pos, const int* __restrict__ eidx,
                float* __restrict__ Hws, float* __restrict__ U3ws,
                float* __restrict__ U2ws, float* __restrict__ U1ws,
                u16* __restrict__ wbws, float4* __restrict__ posf,
                int* __restrict__ cur, u16* __restrict__ el16)
{
  int tid = threadIdx.x;
  int b = blockIdx.x;
  int bf = sniff_wave((const u32*)Wu, tid & 63);

  // fused padded scatter: one edge per thread (1250*256 = NE)
  {
    int e = b*256 + tid;
    int r = eidx[NE + e];
    int s = eidx[e];
    int slot = atomicAdd(&cur[r], 1);
    if (slot < 64) el16[(r << 6) + slot] = (u16)s;
  }

  if (b == 0){
    for (int t = tid; t < 36; t += 256) U1ws[t] = ldf(U1, t, bf);
    for (int t = tid; t < 45; t += 256){
      int j = 0, rem = t;
      for (;;){ int cnt = 9 - j; if (rem < cnt) break; rem -= cnt; ++j; }
      int k = j + rem;
      for (int p = 0; p < 4; ++p){
        float v = ldf(U2, (j*9 + k)*4 + p, bf);
        if (k > j) v += ldf(U2, (k*9 + j)*4 + p, bf);
        U2ws[t*4 + p] = v;
      }
    }
    for (int t = tid; t < 165; t += 256){
      int i = 0, rem = t;
      for (;;){ int m = 9 - i; int cnt = m*(m+1)/2; if (rem < cnt) break; rem -= cnt; ++i; }
      int j = i;
      for (;;){ int cnt = 9 - j; if (rem < cnt) break; rem -= cnt; ++j; }
      int k = j + rem;
      int pm[6][3] = {{i,j,k},{i,k,j},{j,i,k},{j,k,i},{k,i,j},{k,j,i}};
      float acc[4] = {0,0,0,0};
      for (int m = 0; m < 6; ++m){
        bool dup = false;
        for (int mm = 0; mm < m; ++mm)
          if (pm[mm][0]==pm[m][0] && pm[mm][1]==pm[m][1] && pm[mm][2]==pm[m][2]) dup = true;
        if (!dup){
          int base = ((pm[m][0]*9 + pm[m][1])*9 + pm[m][2])*4;
          for (int p = 0; p < 4; ++p) acc[p] += ldf(U3, base + p, bf);
        }
      }
      for (int p = 0; p < 4; ++p) U3ws[t*4 + p] = acc[p];
    }
  } else if (b <= 88){
    // B-frag pack (16x16x32): lane L holds B[k=(L>>4)*8+j][n=L&15]
    int idx = (b - 1)*256 + tid;
    int f = idx >> 9;
    int L = (idx >> 3) & 63;
    int j = idx & 7;
    int kl = ((L >> 4) << 3) + j;
    int n16 = L & 15;
    float v;
    if (f < 4){
      v = (kl < 8) ? ldf(w1, kl*64 + (f*16 + n16), bf) : 0.f;
    } else if (f < 12){
      int g = f - 4; int t = g >> 1, q = g & 1;
      v = ldf(w2, (q*32 + kl)*64 + (t*16 + n16), bf);
    } else if (f < 20){
      int g = f - 12; int t = g >> 1, q = g & 1;
      v = ldf(w3, (q*32 + kl)*64 + (t*16 + n16), bf);
    } else {
      int g = f - 20; int lt = g >> 1, q = g & 1;
      int l = lt >> 2, ct = lt & 3;
      v = ldf(w4, (q*32 + kl)*192 + (l*64 + ct*16 + n16), bf);
    }
    wbws[idx] = f2bf(v);
  } else if (b <= 167){
    int i = (b - 89)*256 + tid;
    if (i < NN){
      float4 v;
      v.x = ldf(pos, 3*i+0, bf); v.y = ldf(pos, 3*i+1, bf); v.z = ldf(pos, 3*i+2, bf); v.w = 0.f;
      posf[i] = v;
    }
  } else if (b <= 177){
    int z = b - 168;
    int c = tid;
    if (c < 64){
      float s = 0.f;
      for (int k = 0; k < 64; ++k) s += ldf(We, z*64 + k, bf) * ldf(Wu, k*64 + c, bf);
      Hws[z*64 + c] = s * 0.0395284708f;   // 1/sqrt(Z*C)
    }
  }
}

// ---------------- edge geometry ----------------
__device__ __forceinline__ void edge_geom(float4 pr, float4 ps, float* ef, float* Y)
{
  float vx = pr.x - ps.x, vy = pr.y - ps.y, vz = pr.z - ps.z;
  float r2 = vx*vx + vy*vy + vz*vz + 1e-12f;
  float rinv = rsqrtf(r2);
  float r = r2 * rinv;
  float ux = vx*rinv, uy = vy*rinv, uz = vz*rinv;
  const float s3 = 1.7320508076f, s5 = 2.2360679775f, s15 = 3.8729833462f;
  Y[0] = 1.0f;
  Y[1] = s3*ux; Y[2] = s3*uy; Y[3] = s3*uz;
  Y[4] = s15*ux*uy; Y[5] = s15*uy*uz;
  Y[6] = 0.5f*s5*(3.0f*uz*uz - 1.0f);
  Y[7] = s15*ux*uz;
  Y[8] = 0.5f*s15*(ux*ux - uy*uy);
  float u = r * 0.2f; u = fminf(u, 1.0f);
  float u2 = u*u, u4 = u2*u2, u6 = u4*u2, u7 = u6*u, u8 = u7*u;
  float fc = 1.0f - 28.0f*u6 + 48.0f*u7 - 21.0f*u8;
  float c0 = 0.63245553203f * fc * rinv;
  float w = 0.62831853072f * r;
  #pragma unroll
  for (int k = 0; k < 8; ++k) ef[k] = c0 * __sinf(w * (float)(k + 1));
}

// ---------------- main: MFMA edge-tile MLP ----------------
// R28: R27 base (best verified: 192.9 us) + software-pipelined L4 P-exchange.
// The three l-iterations' dd-MFMAs are independent (only X-accumulation orders
// them); the old loop exposed 3 serialized ds_write->ds_read round trips
// (~120cy each) per tile. New schedule with a second P buffer aliased onto act
// (a0/a1 already in registers; act dead until next tile's L1 store):
//   dd(l0)->write A; dd(l1)->write B   <- l1 MFMAs hide A's write latency
//   read A -> X-MFMA(l0)
//   dd(l2)->write A                    <- anti-dep safe: DS in-order per wave
//   read B -> X-MFMA(l1); read A -> X-MFMA(l2)
// Hides 2 of 3 round trips per tile under MFMA work. No LDS/register growth.
// Accepted: ~164MB scratch WRITE (one 32-dword weight array written once/wave,
// L2-resident re-reads — drain BW not critical path).
// Proven dead ends: occupancy >3 blocks (spills), VALU-count cuts (no dur
// change), node batching (2.5x regression).
extern "C" __global__ __launch_bounds__(256, 3)
void k_main(const int* __restrict__ atom,
            const void* __restrict__ Wu,
            const void* __restrict__ Wc3, const void* __restrict__ Wc2, const void* __restrict__ Wc1,
            const void* __restrict__ Woutg,
            const float* __restrict__ Hws, const float* __restrict__ U3ws,
            const float* __restrict__ U2ws, const float* __restrict__ U1ws,
            const float4* __restrict__ posf,
            const int* __restrict__ deg, const u16* __restrict__ el16,
            const u16* __restrict__ wbws, void* __restrict__ outp)
{
  __shared__ __align__(16) u16   wb[12288];         // 24 w4 B-frags, 24576 B
  __shared__ __align__(16) float Hs[10][64];        // 2560 B
  __shared__ __align__(16) u16   efb[4][64][8];     // 4096 B
  __shared__ __align__(16) u16   zb64[4][64];       // 512 B
  __shared__ __align__(16) u16   act[4][1024];      // 8192 B  swizzled [16][64]; P-buf B aliases here
  __shared__ __align__(16) u16   Yc[4][64][9];      // 4608 B  compact Y
  __shared__ __align__(16) u16   pfrag[4][4][32][8];// 8192 B  P A-frags buf A
  // total 52,736 B; 3 blocks/CU (reg-bound anyway)

  int tid = threadIdx.x;
  int wv = tid >> 6;
  int lane = tid & 63;
  int bf = sniff_wave((const u32*)Wu, lane);

  int c0 = lane & 15;
  int qd = lane >> 4;
  int n = blockIdx.x * 4 + wv;

  // ---- gather chain issued ASAP (latency hides under staging + hoists) ----
  int cnt = min(deg[n], 64);
  int el  = (int)el16[(n << 6) + lane];   // padded row, always safe
  float4 pr = posf[n];

  // stage w4 frags (orig frag 20..43 -> uint4 offset 1280) as b128 copies
  for (int t = tid; t < 1536; t += 256)
    ((uint4*)wb)[t] = ((const uint4*)wbws)[1280 + t];
  if (tid < 160) ((float4*)Hs)[tid] = ((const float4*)Hws)[tid];

  bool valid = lane < cnt;
  int sid = valid ? el : n;
  float4 ps = posf[sid];
  int z = valid ? atom[sid] : 0;

  // hoisted w1/w2/w3 B-frags (registers; loop-invariant)
  bf16x8 w1p[4], w2p[8], w3p[8];
  #pragma unroll
  for (int t = 0; t < 4; ++t) w1p[t] = *(const bf16x8*)&wbws[t*512 + lane*8];
  #pragma unroll
  for (int g = 0; g < 8; ++g) w2p[g] = *(const bf16x8*)&wbws[(4+g)*512 + lane*8];
  #pragma unroll
  for (int g = 0; g < 8; ++g) w3p[g] = *(const bf16x8*)&wbws[(12+g)*512 + lane*8];

  // ---- geometry + per-wave LDS writes (efb/Yc/zb64 disjoint from wb/Hs) ----
  {
    float ef[8], Y[9];
    edge_geom(pr, ps, ef, Y);
    if (!valid){
      #pragma unroll
      for (int k = 0; k < 8; ++k) ef[k] = 0.f;
      #pragma unroll
      for (int m = 0; m < 9; ++m) Y[m] = 0.f;
    }
    uint4 pk;
    pk.x = pk2bf(ef[0], ef[1]);
    pk.y = pk2bf(ef[2], ef[3]);
    pk.z = pk2bf(ef[4], ef[5]);
    pk.w = pk2bf(ef[6], ef[7]);
    *(uint4*)&efb[wv][lane][0] = pk;
    #pragma unroll
    for (int m = 0; m < 9; ++m) Yc[wv][lane][m] = f2bf(Y[m]);
    zb64[wv][lane] = (u16)z;
  }
  __syncthreads();   // covers wb/Hs staging AND the per-wave efb/Yc/zb64 writes

  u16* A = &act[wv][0];
  int swr = qd << 4;            // write swizzle: row = qd*4+r -> row>>2 == qd
  int srd = (c0 >> 2) << 4;     // read swizzle:  row = c0

  int lmap = (c0 == 0) ? 0 : (c0 < 4) ? 1 : 2;
  u32 msk0 = (lmap == 0) ? 0xFFFFFFFFu : 0u;
  u32 msk1 = (lmap == 1) ? 0xFFFFFFFFu : 0u;
  u32 msk2 = (lmap == 2) ? 0xFFFFFFFFu : 0u;

  const f32x4 zero4 = {0.f, 0.f, 0.f, 0.f};
  f32x4 XD[4];
  #pragma unroll
  for (int t = 0; t < 4; ++t) XD[t] = zero4;

  int prow = ((qd >> 1) << 4) + c0;
  int pcol = (qd & 1) << 2;
  int ntile = (cnt + 15) >> 4;

  #pragma unroll 1
  for (int t = 0; t < ntile; ++t){
    f32x4 dd[4];

    // ---- L1 ----
    bf16x8 aF = {0,0,0,0,0,0,0,0};
    if (lane < 16) aF = *(const bf16x8*)&efb[wv][t*16 + lane][0];
    #pragma unroll
    for (int t2 = 0; t2 < 4; ++t2) dd[t2] = mfma16(aF, w1p[t2], zero4);
    #pragma unroll
    for (int t2 = 0; t2 < 4; ++t2)
      #pragma unroll
      for (int r = 0; r < 4; ++r)
        A[(((qd*4 + r) << 6) + c0 + (t2 << 4)) ^ swr] = f2bfa(silu_f(dd[t2][r]));
    SOFT_FENCE();

    // ---- L2 ----
    bf16x8 a0 = *(const bf16x8*)&A[((c0 << 6) + (qd << 3)) ^ srd];
    bf16x8 a1 = *(const bf16x8*)&A[((c0 << 6) + 32 + (qd << 3)) ^ srd];
    #pragma unroll
    for (int t2 = 0; t2 < 4; ++t2)
      dd[t2] = mfma16(a1, w2p[t2*2+1], mfma16(a0, w2p[t2*2+0], zero4));
    #pragma unroll
    for (int t2 = 0; t2 < 4; ++t2)
      #pragma unroll
      for (int r = 0; r < 4; ++r)
        A[(((qd*4 + r) << 6) + c0 + (t2 << 4)) ^ swr] = f2bfa(silu_f(dd[t2][r]));
    SOFT_FENCE();

    // ---- L3 (w3 in registers) ----
    a0 = *(const bf16x8*)&A[((c0 << 6) + (qd << 3)) ^ srd];
    a1 = *(const bf16x8*)&A[((c0 << 6) + 32 + (qd << 3)) ^ srd];
    #pragma unroll
    for (int t2 = 0; t2 < 4; ++t2)
      dd[t2] = mfma16(a1, w3p[t2*2+1], mfma16(a0, w3p[t2*2+0], zero4));
    #pragma unroll
    for (int t2 = 0; t2 < 4; ++t2)
      #pragma unroll
      for (int r = 0; r < 4; ++r)
        A[(((qd*4 + r) << 6) + c0 + (t2 << 4)) ^ swr] = f2bfa(silu_f(dd[t2][r]));
    SOFT_FENCE();

    // ---- L4 + X-MFMA (software-pipelined P exchange) ----
    a0 = *(const bf16x8*)&A[((c0 << 6) + (qd << 3)) ^ srd];
    a1 = *(const bf16x8*)&A[((c0 << 6) + 32 + (qd << 3)) ^ srd];

    // rebuild Y B-frag in registers: elem j = Y[(lane>>4)*8+j][c0]
    u32 yd0 = 0, yd1 = 0, yd2 = 0, yd3 = 0;
    if (lane < 32 && c0 < 9){
      const u16* yr = &Yc[wv][t*16 + ((lane >> 4) << 3)][0];
      yd0 = (u32)yr[0*9 + c0] | ((u32)yr[1*9 + c0] << 16);
      yd1 = (u32)yr[2*9 + c0] | ((u32)yr[3*9 + c0] << 16);
      yd2 = (u32)yr[4*9 + c0] | ((u32)yr[5*9 + c0] << 16);
      yd3 = (u32)yr[6*9 + c0] | ((u32)yr[7*9 + c0] << 16);
    }
    bf16x8 B0, B1, B2;
    { uint4 t0 = {yd0 & msk0, yd1 & msk0, yd2 & msk0, yd3 & msk0};
      uint4 t1 = {yd0 & msk1, yd1 & msk1, yd2 & msk1, yd3 & msk1};
      uint4 t2 = {yd0 & msk2, yd1 & msk2, yd2 & msk2, yd3 & msk2};
      B0 = *(bf16x8*)&t0; B1 = *(bf16x8*)&t1; B2 = *(bf16x8*)&t2; }

    float hv[4][4];
    #pragma unroll
    for (int r = 0; r < 4; ++r){
      int z_e = (int)zb64[wv][t*16 + qd*4 + r];
      #pragma unroll
      for (int ct = 0; ct < 4; ++ct) hv[r][ct] = Hs[z_e][ct*16 + c0];
    }

    u16* PB = A;   // second P buffer aliases act (a0/a1 already in registers)

    // l=0: dd -> pfrag (buf A)
    #pragma unroll
    for (int ct = 0; ct < 4; ++ct){
      int f = ct*2;
      bf16x8 b0 = *(const bf16x8*)&wb[f*512 + lane*8];
      bf16x8 b1 = *(const bf16x8*)&wb[(f+1)*512 + lane*8];
      dd[ct] = mfma16(a1, b1, mfma16(a0, b0, zero4));
    }
    #pragma unroll
    for (int ct = 0; ct < 4; ++ct){
      uint2 pk2;
      pk2.x = pk2bf(hv[0][ct] * dd[ct][0], hv[1][ct] * dd[ct][1]);
      pk2.y = pk2bf(hv[2][ct] * dd[ct][2], hv[3][ct] * dd[ct][3]);
      *(uint2*)&pfrag[wv][ct][prow][pcol] = pk2;
    }
    // l=1: dd -> PB (buf B); these MFMAs hide buf A's write latency
    #pragma unroll
    for (int ct = 0; ct < 4; ++ct){
      int f = (4 + ct)*2;
      bf16x8 b0 = *(const bf16x8*)&wb[f*512 + lane*8];
      bf16x8 b1 = *(const bf16x8*)&wb[(f+1)*512 + lane*8];
      dd[ct] = mfma16(a1, b1, mfma16(a0, b0, zero4));
    }
    #pragma unroll
    for (int ct = 0; ct < 4; ++ct){
      uint2 pk2;
      pk2.x = pk2bf(hv[0][ct] * dd[ct][0], hv[1][ct] * dd[ct][1]);
      pk2.y = pk2bf(hv[2][ct] * dd[ct][2], hv[3][ct] * dd[ct][3]);
      *(uint2*)&PB[ct*256 + prow*8 + pcol] = pk2;
    }
    SOFT_FENCE();
    // X-MFMA l=0 (buf A)
    #pragma unroll
    for (int ct = 0; ct < 4; ++ct){
      bf16x8 aP = {0,0,0,0,0,0,0,0};
      if (lane < 32) aP = *(const bf16x8*)&pfrag[wv][ct][lane][0];
      XD[ct] = mfma16(aP, B0, XD[ct]);
    }
    SOFT_FENCE();
    // l=2: dd -> pfrag (buf A reuse; anti-dep safe: l0 reads issued earlier, DS in-order)
    #pragma unroll
    for (int ct = 0; ct < 4; ++ct){
      int f = (8 + ct)*2;
      bf16x8 b0 = *(const bf16x8*)&wb[f*512 + lane*8];
      bf16x8 b1 = *(const bf16x8*)&wb[(f+1)*512 + lane*8];
      dd[ct] = mfma16(a1, b1, mfma16(a0, b0, zero4));
    }
    #pragma unroll
    for (int ct = 0; ct < 4; ++ct){
      uint2 pk2;
      pk2.x = pk2bf(hv[0][ct] * dd[ct][0], hv[1][ct] * dd[ct][1]);
      pk2.y = pk2bf(hv[2][ct] * dd[ct][2], hv[3][ct] * dd[ct][3]);
      *(uint2*)&pfrag[wv][ct][prow][pcol] = pk2;
    }
    SOFT_FENCE();
    // X-MFMA l=1 (buf B)
    #pragma unroll
    for (int ct = 0; ct < 4; ++ct){
      bf16x8 aP = {0,0,0,0,0,0,0,0};
      if (lane < 32) aP = *(const bf16x8*)&PB[ct*256 + lane*8];
      XD[ct] = mfma16(aP, B1, XD[ct]);
    }
    SOFT_FENCE();
    // X-MFMA l=2 (buf A)
    #pragma unroll
    for (int ct = 0; ct < 4; ++ct){
      bf16x8 aP = {0,0,0,0,0,0,0,0};
      if (lane < 32) aP = *(const bf16x8*)&pfrag[wv][ct][lane][0];
      XD[ct] = mfma16(aP, B2, XD[ct]);
    }
    SOFT_FENCE();   // PB reads done before next tile's L1 writes act
  }

  // ---- redistribute X: D-frags -> Xf8 (act slice) + X8f (efb slice) ----
  float* Xf8 = (float*)A;                 // [64][8] f32 = 2048 B
  float* X8f = (float*)&efb[wv][0][0];    // [64] f32 = 256 B
  SOFT_FENCE();
  #pragma unroll
  for (int ct = 0; ct < 4; ++ct)
    #pragma unroll
    for (int r = 0; r < 4; ++r){
      int c = ct*16 + qd*4 + r;
      if (c0 < 8)       Xf8[c*8 + c0] = XD[ct][r];
      else if (c0 == 8) X8f[c]        = XD[ct][r];
    }
  SOFT_FENCE();
  float X[9];
  {
    const float4* xr = (const float4*)&Xf8[lane*8];
    float4 xa = xr[0], xb = xr[1];
    X[0]=xa.x; X[1]=xa.y; X[2]=xa.z; X[3]=xa.w;
    X[4]=xb.x; X[5]=xb.y; X[6]=xb.z; X[7]=xb.w;
    X[8]=X8f[lane];
  }
  #pragma unroll
  for (int m = 0; m < 9; ++m) X[m] *= 0.0625f;   // / AVG

  // ---- contraction (f32x4 accumulators -> v_pk_fma_f32 pairs) ----
  const f32x4* U1g = (const f32x4*)U1ws;
  const f32x4* U2g = (const f32x4*)U2ws;
  const f32x4* U3g = (const f32x4*)U3ws;
  f32x4 s1 = zero4, s2 = zero4, s3 = zero4;
  #pragma unroll
  for (int j = 0; j < 9; ++j) s1 += U1g[j] * X[j];
  {
    int t2i = 0;
    #pragma unroll
    for (int j = 0; j < 9; ++j)
      #pragma unroll
      for (int k = j; k < 9; ++k){
        float m = X[j]*X[k];
        s2 += U2g[t2i] * m; ++t2i;
      }
  }
  {
    int t3i = 0;
    #pragma unroll
    for (int i = 0; i < 9; ++i)
      #pragma unroll
      for (int j = i; j < 9; ++j){
        float mij = X[i]*X[j];
        #pragma unroll
        for (int k = j; k < 9; ++k){
          s3 += U3g[t3i] * (mij*X[k]); ++t3i;
        }
      }
  }

  int zn = atom[n];
  float outval = 0.f;
  #pragma unroll
  for (int p = 0; p < 4; ++p){
    int b = (zn*4 + p)*64 + lane;
    outval += ldf(Wc1, b, bf)*s1[p] + ldf(Wc2, b, bf)*s2[p] + ldf(Wc3, b, bf)*s3[p];
  }

  // ---- final matmul (xchg reuses act slice after Xf8 consumed) ----
  float* xchg = (float*)A;
  SOFT_FENCE();
  xchg[lane] = outval;
  SOFT_FENCE();
  float acc = 0.f;
  const float4* pb = (const float4*)xchg;
  if (bf){
    const u16* wg = (const u16*)Woutg;
    #pragma unroll
    for (int cb = 0; cb < 16; ++cb){
      float4 p = pb[cb];
      acc += p.x*bf2f(wg[(4*cb+0)*64 + lane]) + p.y*bf2f(wg[(4*cb+1)*64 + lane])
           + p.z*bf2f(wg[(4*cb+2)*64 + lane]) + p.w*bf2f(wg[(4*cb+3)*64 + lane]);
    }
  } else {
    const float* wg = (const float*)Woutg;
    #pragma unroll
    for (int cb = 0; cb < 16; ++cb){
      float4 p = pb[cb];
      acc += p.x*wg[(4*cb+0)*64 + lane] + p.y*wg[(4*cb+1)*64 + lane]
           + p.z*wg[(4*cb+2)*64 + lane] + p.w*wg[(4*cb+3)*64 + lane];
    }
  }
  acc *= 0.125f;
  if (bf) ((u16*)outp)[n*64 + lane] = f2bf(acc);
  else    ((float*)outp)[n*64 + lane] = acc;
}

// ---------------- host ----------------
extern "C" void kernel_launch(void* const* d_in, const int* in_sizes, int n_in,
                              void* d_out, int out_size, void* d_ws, size_t ws_size,
                              hipStream_t stream)
{
  const void* pos  = d_in[0];
  const int* atom  = (const int*)d_in[1];
  const int* eidx  = (const int*)d_in[2];
  const void* We   = d_in[3];
  const void* Wu   = d_in[4];
  const void* w1g  = d_in[5];
  const void* w2g  = d_in[6];
  const void* w3g  = d_in[7];
  const void* w4g  = d_in[8];
  const void* U3   = d_in[9];
  const void* U2   = d_in[10];
  const void* U1   = d_in[11];
  const void* Wc3  = d_in[12];
  const void* Wc2  = d_in[13];
  const void* Wc1  = d_in[14];
  const void* Wout = d_in[15];

  char* ws = (char*)d_ws;
  float*  Hws   = (float*)(ws + WP_H);
  float*  U1ws  = (float*)(ws + WP_U1);
  float*  U2ws  = (float*)(ws + WP_U2);
  float*  U3ws  = (float*)(ws + WP_U3);
  int*    cur   = (int*)(ws + WP_CUR);
  float4* posf  = (float4*)(ws + WP_POSF);
  u16*    wbws  = (u16*)(ws + WP_WB);
  u16*    el16  = (u16*)(ws + WP_EL16);

  (void)hipMemsetAsync(ws + WP_CUR, 0, 80000, stream);
  k_prep_pad<<<1250, 256, 0, stream>>>(We, Wu, U3, U2, U1, w1g, w2g, w3g, w4g, pos, eidx,
                                       Hws, U3ws, U2ws, U1ws, wbws, posf, cur, el16);
  k_main<<<5000, 256, 0, stream>>>(atom, Wu, Wc3, Wc2, Wc1, Wout,
                                   Hws, U3ws, U2ws, U1ws, posf,
                                   cur, el16, wbws, d_out);
}

// Round 11
// 278.052 us; speedup vs baseline: 2.1446x; 1.0121x over previous
//
#include <hip/hip_runtime.h>
#include <hip/hip_bf16.h>

typedef unsigned short u16;
typedef unsigned int u32;
typedef __attribute__((ext_vector_type(8))) short bf16x8;
typedef __attribute__((ext_vector_type(4))) float f32x4;

#define NN 20000
#define NE 320000

// ---------------- workspace layout (padded CSR; ws_size >= 3,012,224 proven) ----------------
#define WP_H     256       // 640 f32
#define WP_U1    3072      // 36 f32
#define WP_U2    3328      // 180 f32
#define WP_U3    4096      // 660 f32
#define WP_CUR   7168      // 20000 i32 (doubles as deg for k_main)
#define WP_POSF  87168     // 20000 float4
#define WP_WB    407168    // 22528 u16
#define WP_EL16  452224    // 20000*64 u16

__device__ __forceinline__ float bf2f(u16 u){ return __uint_as_float(((u32)u) << 16); }
__device__ __forceinline__ u16 f2bf(float f){
  u32 u = __float_as_uint(f);
  u32 r = (u + 0x7fffu + ((u >> 16) & 1u)) >> 16;
  return (u16)r;
}
__device__ __forceinline__ u16 f2bfa(float f){
  return (u16)((__float_as_uint(f) + 0x8000u) >> 16);
}
__device__ __forceinline__ u32 pk2bf(float a, float b){
  __hip_bfloat162 h = __float22bfloat162_rn(make_float2(a, b));
  return *(u32*)&h;
}
__device__ __forceinline__ float silu_f(float v){
  return v * __builtin_amdgcn_rcpf(1.0f + __expf(-v));
}
__device__ __forceinline__ float ldf(const void* p, int i, int bf){
  return bf ? bf2f(((const u16*)p)[i]) : ((const float*)p)[i];
}
__device__ __forceinline__ f32x4 mfma16(bf16x8 a, bf16x8 b, f32x4 c){
  return __builtin_amdgcn_mfma_f32_16x16x32_bf16(a, b, c, 0, 0, 0);
}

// Compiler-only fence for SAME-WAVE LDS exchange: CDNA DS ops from one wave
// complete in program order, so cross-lane RAW within a wave needs no hardware
// drain — only a compiler reordering barrier. Zero cycles.
#define SOFT_FENCE() do { \
  __builtin_amdgcn_wave_barrier(); \
  asm volatile("" ::: "memory"); \
  __builtin_amdgcn_wave_barrier(); \
} while (0)

__device__ __forceinline__ int sniff_wave(const u32* wu, int lane){
  u32 w = wu[lane];
  u32 e = (w >> 7) & 0xFFu;
  unsigned long long m = __ballot(e >= 0x60u && e <= 0x86u);
  return (__popcll(m) > 37) ? 1 : 0;
}

// ---------------- fused prep (grid=1250) — R18-R20 proven, unchanged ----------------
extern "C" __global__ __launch_bounds__(256)
void k_prep_pad(const void* __restrict__ We, const void* __restrict__ Wu,
                const void* __restrict__ U3, const void* __restrict__ U2, const void* __restrict__ U1,
                const void* __restrict__ w1, const void* __restrict__ w2,
                const void* __restrict__ w3, const void* __restrict__ w4,
                const void* __restrict__ pos, const int* __restrict__ eidx,
                float* __restrict__ Hws, float* __restrict__ U3ws,
                float* __restrict__ U2ws, float* __restrict__ U1ws,
                u16* __restrict__ wbws, float4* __restrict__ posf,
                int* __restrict__ cur, u16* __restrict__ el16)
{
  int tid = threadIdx.x;
  int b = blockIdx.x;
  int bf = sniff_wave((const u32*)Wu, tid & 63);

  // fused padded scatter: one edge per thread (1250*256 = NE)
  {
    int e = b*256 + tid;
    int r = eidx[NE + e];
    int s = eidx[e];
    int slot = atomicAdd(&cur[r], 1);
    if (slot < 64) el16[(r << 6) + slot] = (u16)s;
  }

  if (b == 0){
    for (int t = tid; t < 36; t += 256) U1ws[t] = ldf(U1, t, bf);
    for (int t = tid; t < 45; t += 256){
      int j = 0, rem = t;
      for (;;){ int cnt = 9 - j; if (rem < cnt) break; rem -= cnt; ++j; }
      int k = j + rem;
      for (int p = 0; p < 4; ++p){
        float v = ldf(U2, (j*9 + k)*4 + p, bf);
        if (k > j) v += ldf(U2, (k*9 + j)*4 + p, bf);
        U2ws[t*4 + p] = v;
      }
    }
    for (int t = tid; t < 165; t += 256){
      int i = 0, rem = t;
      for (;;){ int m = 9 - i; int cnt = m*(m+1)/2; if (rem < cnt) break; rem -= cnt; ++i; }
      int j = i;
      for (;;){ int cnt = 9 - j; if (rem < cnt) break; rem -= cnt; ++j; }
      int k = j + rem;
      int pm[6][3] = {{i,j,k},{i,k,j},{j,i,k},{j,k,i},{k,i,j},{k,j,i}};
      float acc[4] = {0,0,0,0};
      for (int m = 0; m < 6; ++m){
        bool dup = false;
        for (int mm = 0; mm < m; ++mm)
          if (pm[mm][0]==pm[m][0] && pm[mm][1]==pm[m][1] && pm[mm][2]==pm[m][2]) dup = true;
        if (!dup){
          int base = ((pm[m][0]*9 + pm[m][1])*9 + pm[m][2])*4;
          for (int p = 0; p < 4; ++p) acc[p] += ldf(U3, base + p, bf);
        }
      }
      for (int p = 0; p < 4; ++p) U3ws[t*4 + p] = acc[p];
    }
  } else if (b <= 88){
    // B-frag pack (16x16x32): lane L holds B[k=(L>>4)*8+j][n=L&15]
    int idx = (b - 1)*256 + tid;
    int f = idx >> 9;
    int L = (idx >> 3) & 63;
    int j = idx & 7;
    int kl = ((L >> 4) << 3) + j;
    int n16 = L & 15;
    float v;
    if (f < 4){
      v = (kl < 8) ? ldf(w1, kl*64 + (f*16 + n16), bf) : 0.f;
    } else if (f < 12){
      int g = f - 4; int t = g >> 1, q = g & 1;
      v = ldf(w2, (q*32 + kl)*64 + (t*16 + n16), bf);
    } else if (f < 20){
      int g = f - 12; int t = g >> 1, q = g & 1;
      v = ldf(w3, (q*32 + kl)*64 + (t*16 + n16), bf);
    } else {
      int g = f - 20; int lt = g >> 1, q = g & 1;
      int l = lt >> 2, ct = lt & 3;
      v = ldf(w4, (q*32 + kl)*192 + (l*64 + ct*16 + n16), bf);
    }
    wbws[idx] = f2bf(v);
  } else if (b <= 167){
    int i = (b - 89)*256 + tid;
    if (i < NN){
      float4 v;
      v.x = ldf(pos, 3*i+0, bf); v.y = ldf(pos, 3*i+1, bf); v.z = ldf(pos, 3*i+2, bf); v.w = 0.f;
      posf[i] = v;
    }
  } else if (b <= 177){
    int z = b - 168;
    int c = tid;
    if (c < 64){
      float s = 0.f;
      for (int k = 0; k < 64; ++k) s += ldf(We, z*64 + k, bf) * ldf(Wu, k*64 + c, bf);
      Hws[z*64 + c] = s * 0.0395284708f;   // 1/sqrt(Z*C)
    }
  }
}

// ---------------- edge geometry ----------------
__device__ __forceinline__ void edge_geom(float4 pr, float4 ps, float* ef, float* Y)
{
  float vx = pr.x - ps.x, vy = pr.y - ps.y, vz = pr.z - ps.z;
  float r2 = vx*vx + vy*vy + vz*vz + 1e-12f;
  float rinv = rsqrtf(r2);
  float r = r2 * rinv;
  float ux = vx*rinv, uy = vy*rinv, uz = vz*rinv;
  const float s3 = 1.7320508076f, s5 = 2.2360679775f, s15 = 3.8729833462f;
  Y[0] = 1.0f;
  Y[1] = s3*ux; Y[2] = s3*uy; Y[3] = s3*uz;
  Y[4] = s15*ux*uy; Y[5] = s15*uy*uz;
  Y[6] = 0.5f*s5*(3.0f*uz*uz - 1.0f);
  Y[7] = s15*ux*uz;
  Y[8] = 0.5f*s15*(ux*ux - uy*uy);
  float u = r * 0.2f; u = fminf(u, 1.0f);
  float u2 = u*u, u4 = u2*u2, u6 = u4*u2, u7 = u6*u, u8 = u7*u;
  float fc = 1.0f - 28.0f*u6 + 48.0f*u7 - 21.0f*u8;
  float c0 = 0.63245553203f * fc * rinv;
  float w = 0.62831853072f * r;
  #pragma unroll
  for (int k = 0; k < 8; ++k) ef[k] = c0 * __sinf(w * (float)(k + 1));
}

// ---------------- main: MFMA edge-tile MLP ----------------
// R29: targets the one untested resource cell {4 blocks/CU, no spill}.
// Occupancy model (fits R20-R28): blocks = min(floor(512/(archVGPR+~48 AGPR))
// per 4-wave block, floor(163840/LDS)). R24 missed 4 blocks by 4 arch regs
// (84 > 80). This round reduces NATURAL arch pressure (no launch_bounds cap —
// those always spilled): w1/w2 frags are re-loaded per tile from L1-hot wbws,
// with an opaque SGPR offset (asm "+s") defeating LICM re-hoisting; w3p stays
// hoisted. Combined with the R24-verified 40,960-B LDS diet (pfrag aliases
// act, Yc8 compact Y[1..8], z via __shfl, hv from global Hws) and R27's
// verified gather-hoist + f32x4 contraction + b128 staging.
// R28's 2-buffer P pipeline dropped (needs 8KB; was worth only ~1 us — TLP
// already hides those round trips, more so at 16 waves/CU).
// PRE-COMMIT: if VGPR >= 84 or occupancy stays ~29%, this cell is unreachable
// at this code shape -> ROOFLINE write-up next round.
extern "C" __global__ __launch_bounds__(256, 3)
void k_main(const int* __restrict__ atom,
            const void* __restrict__ Wu,
            const void* __restrict__ Wc3, const void* __restrict__ Wc2, const void* __restrict__ Wc1,
            const void* __restrict__ Woutg,
            const float* __restrict__ Hws, const float* __restrict__ U3ws,
            const float* __restrict__ U2ws, const float* __restrict__ U1ws,
            const float4* __restrict__ posf,
            const int* __restrict__ deg, const u16* __restrict__ el16,
            const u16* __restrict__ wbws, void* __restrict__ outp)
{
  __shared__ __align__(16) u16   wb[12288];        // 24576 B  24 w4 B-frags (block-shared)
  __shared__ __align__(16) u16   act[4][1024];     // 8192 B   swizzled [16][64]; pfrag/Xf8/xchg alias
  __shared__ __align__(16) u16   efb[4][64][8];    // 4096 B   ef; X8f aliases here
  __shared__ __align__(16) u16   Yc8[4][64][8];    // 4096 B   Y[1..8] compact
  // total 40,960 B -> 4 blocks/CU by LDS

  int tid = threadIdx.x;
  int wv = tid >> 6;
  int lane = tid & 63;
  int bf = sniff_wave((const u32*)Wu, lane);

  int c0 = lane & 15;
  int qd = lane >> 4;
  int n = blockIdx.x * 4 + wv;

  // ---- gather chain issued ASAP (latency hides under staging) ----
  int cnt = min(deg[n], 64);
  int el  = (int)el16[(n << 6) + lane];   // padded row, always safe
  float4 pr = posf[n];

  // stage w4 frags (orig frag 20..43 -> uint4 offset 1280) as b128 copies
  for (int t = tid; t < 1536; t += 256)
    ((uint4*)wb)[t] = ((const uint4*)wbws)[1280 + t];

  bool valid = lane < cnt;
  int sid = valid ? el : n;
  float4 ps = posf[sid];
  int zreg = valid ? atom[sid] : 0;

  // w3p only hoisted (32 VGPRs); w1/w2 re-loaded per tile (opaque offset)
  bf16x8 w3p[8];
  #pragma unroll
  for (int g = 0; g < 8; ++g) w3p[g] = *(const bf16x8*)&wbws[(12+g)*512 + lane*8];

  // ---- geometry + per-wave LDS writes (efb/Yc8 disjoint from wb) ----
  {
    float ef[8], Y[9];
    edge_geom(pr, ps, ef, Y);
    if (!valid){
      #pragma unroll
      for (int k = 0; k < 8; ++k) ef[k] = 0.f;
      #pragma unroll
      for (int m = 0; m < 9; ++m) Y[m] = 0.f;
    }
    uint4 pk;
    pk.x = pk2bf(ef[0], ef[1]);
    pk.y = pk2bf(ef[2], ef[3]);
    pk.z = pk2bf(ef[4], ef[5]);
    pk.w = pk2bf(ef[6], ef[7]);
    *(uint4*)&efb[wv][lane][0] = pk;
    uint4 yp;
    yp.x = pk2bf(Y[1], Y[2]);
    yp.y = pk2bf(Y[3], Y[4]);
    yp.z = pk2bf(Y[5], Y[6]);
    yp.w = pk2bf(Y[7], Y[8]);
    *(uint4*)&Yc8[wv][lane][0] = yp;
  }
  __syncthreads();   // covers wb staging AND per-wave efb/Yc8 writes

  u16* A = &act[wv][0];
  int swr = qd << 4;            // write swizzle: row = qd*4+r -> row>>2 == qd
  int srd = (c0 >> 2) << 4;     // read swizzle:  row = c0

  int lmap = (c0 == 0) ? 0 : (c0 < 4) ? 1 : 2;
  u32 msk1 = (lmap == 1) ? 0xFFFFFFFFu : 0u;
  u32 msk2 = (lmap == 2) ? 0xFFFFFFFFu : 0u;

  const f32x4 zero4 = {0.f, 0.f, 0.f, 0.f};
  f32x4 XD[4];
  #pragma unroll
  for (int t = 0; t < 4; ++t) XD[t] = zero4;

  int prow = ((qd >> 1) << 4) + c0;
  int pcol = (qd & 1) << 2;
  int ntile = (cnt + 15) >> 4;

  u32 zofs = 0;   // opaque offset: defeats LICM so w1/w2 loads re-issue per tile

  #pragma unroll 1
  for (int t = 0; t < ntile; ++t){
    asm volatile("" : "+s"(zofs));
    f32x4 dd[4];

    // ---- L1 (w1 frags from L1-hot global, not hoisted) ----
    bf16x8 aF = {0,0,0,0,0,0,0,0};
    if (lane < 16) aF = *(const bf16x8*)&efb[wv][t*16 + lane][0];
    #pragma unroll
    for (int t2 = 0; t2 < 4; ++t2){
      bf16x8 w1f = *(const bf16x8*)&wbws[zofs + t2*512 + lane*8];
      dd[t2] = mfma16(aF, w1f, zero4);
    }
    #pragma unroll
    for (int t2 = 0; t2 < 4; ++t2)
      #pragma unroll
      for (int r = 0; r < 4; ++r)
        A[(((qd*4 + r) << 6) + c0 + (t2 << 4)) ^ swr] = f2bfa(silu_f(dd[t2][r]));
    SOFT_FENCE();

    // ---- L2 (w2 frags from L1-hot global, not hoisted) ----
    bf16x8 a0 = *(const bf16x8*)&A[((c0 << 6) + (qd << 3)) ^ srd];
    bf16x8 a1 = *(const bf16x8*)&A[((c0 << 6) + 32 + (qd << 3)) ^ srd];
    #pragma unroll
    for (int t2 = 0; t2 < 4; ++t2){
      bf16x8 w2a = *(const bf16x8*)&wbws[zofs + (4 + t2*2)*512 + lane*8];
      bf16x8 w2b = *(const bf16x8*)&wbws[zofs + (5 + t2*2)*512 + lane*8];
      dd[t2] = mfma16(a1, w2b, mfma16(a0, w2a, zero4));
    }
    #pragma unroll
    for (int t2 = 0; t2 < 4; ++t2)
      #pragma unroll
      for (int r = 0; r < 4; ++r)
        A[(((qd*4 + r) << 6) + c0 + (t2 << 4)) ^ swr] = f2bfa(silu_f(dd[t2][r]));
    SOFT_FENCE();

    // ---- L3 (w3 in registers) ----
    a0 = *(const bf16x8*)&A[((c0 << 6) + (qd << 3)) ^ srd];
    a1 = *(const bf16x8*)&A[((c0 << 6) + 32 + (qd << 3)) ^ srd];
    #pragma unroll
    for (int t2 = 0; t2 < 4; ++t2)
      dd[t2] = mfma16(a1, w3p[t2*2+1], mfma16(a0, w3p[t2*2+0], zero4));
    #pragma unroll
    for (int t2 = 0; t2 < 4; ++t2)
      #pragma unroll
      for (int r = 0; r < 4; ++r)
        A[(((qd*4 + r) << 6) + c0 + (t2 << 4)) ^ swr] = f2bfa(silu_f(dd[t2][r]));
    SOFT_FENCE();

    // ---- L4 + X-MFMA ----
    a0 = *(const bf16x8*)&A[((c0 << 6) + (qd << 3)) ^ srd];
    a1 = *(const bf16x8*)&A[((c0 << 6) + 32 + (qd << 3)) ^ srd];

    // Y B-frag rebuild: Yc8 holds m=1..8; m=0 column = 1.0 * (row < cnt)
    u32 yd0 = 0, yd1 = 0, yd2 = 0, yd3 = 0;
    if (lane < 32 && c0 >= 1 && c0 <= 8){
      const u16* yr = &Yc8[wv][t*16 + ((lane >> 4) << 3)][c0 - 1];
      yd0 = (u32)yr[0*8] | ((u32)yr[1*8] << 16);
      yd1 = (u32)yr[2*8] | ((u32)yr[3*8] << 16);
      yd2 = (u32)yr[4*8] | ((u32)yr[5*8] << 16);
      yd3 = (u32)yr[6*8] | ((u32)yr[7*8] << 16);
    }
    u32 b00 = 0, b01 = 0, b02 = 0, b03 = 0;
    if (lane < 32 && c0 == 0){
      int k0 = t*16 + ((lane >> 4) << 3);
      b00 = ((k0+0 < cnt) ? 0x3F80u : 0u) | ((k0+1 < cnt) ? 0x3F800000u : 0u);
      b01 = ((k0+2 < cnt) ? 0x3F80u : 0u) | ((k0+3 < cnt) ? 0x3F800000u : 0u);
      b02 = ((k0+4 < cnt) ? 0x3F80u : 0u) | ((k0+5 < cnt) ? 0x3F800000u : 0u);
      b03 = ((k0+6 < cnt) ? 0x3F80u : 0u) | ((k0+7 < cnt) ? 0x3F800000u : 0u);
    }
    bf16x8 B0, B1, B2;
    { uint4 t0 = {b00, b01, b02, b03};
      uint4 t1 = {yd0 & msk1, yd1 & msk1, yd2 & msk1, yd3 & msk1};
      uint4 t2 = {yd0 & msk2, yd1 & msk2, yd2 & msk2, yd3 & msk2};
      B0 = *(bf16x8*)&t0; B1 = *(bf16x8*)&t1; B2 = *(bf16x8*)&t2; }

    float hv[4][4];
    #pragma unroll
    for (int r = 0; r < 4; ++r){
      int z_e = __shfl(zreg, t*16 + qd*4 + r);
      #pragma unroll
      for (int ct = 0; ct < 4; ++ct) hv[r][ct] = Hws[z_e*64 + ct*16 + c0];
    }

    u16* PF = A;   // pfrag aliases act: [ct][32][8] u16 = 2048 B per wave
    #pragma unroll
    for (int l = 0; l < 3; ++l){
      #pragma unroll
      for (int ct = 0; ct < 4; ++ct){
        int f = (l*4 + ct)*2;
        bf16x8 b0 = *(const bf16x8*)&wb[f*512 + lane*8];
        bf16x8 b1 = *(const bf16x8*)&wb[(f+1)*512 + lane*8];
        dd[ct] = mfma16(a1, b1, mfma16(a0, b0, zero4));
      }
      #pragma unroll
      for (int ct = 0; ct < 4; ++ct){
        uint2 pk2;
        pk2.x = pk2bf(hv[0][ct] * dd[ct][0], hv[1][ct] * dd[ct][1]);
        pk2.y = pk2bf(hv[2][ct] * dd[ct][2], hv[3][ct] * dd[ct][3]);
        *(uint2*)&PF[ct*256 + prow*8 + pcol] = pk2;
      }
      SOFT_FENCE();
      bf16x8 Bl = (l == 0) ? B0 : (l == 1) ? B1 : B2;
      #pragma unroll
      for (int ct = 0; ct < 4; ++ct){
        bf16x8 aP = {0,0,0,0,0,0,0,0};
        if (lane < 32) aP = *(const bf16x8*)&PF[ct*256 + lane*8];
        XD[ct] = mfma16(aP, Bl, XD[ct]);
      }
      SOFT_FENCE();
    }
  }

  // ---- redistribute X: D-frags -> Xf8 (act slice) + X8f (efb slice) ----
  float* Xf8 = (float*)A;                 // [64][8] f32 = 2048 B
  float* X8f = (float*)&efb[wv][0][0];    // [64] f32 = 256 B
  SOFT_FENCE();
  #pragma unroll
  for (int ct = 0; ct < 4; ++ct)
    #pragma unroll
    for (int r = 0; r < 4; ++r){
      int c = ct*16 + qd*4 + r;
      if (c0 < 8)       Xf8[c*8 + c0] = XD[ct][r];
      else if (c0 == 8) X8f[c]        = XD[ct][r];
    }
  SOFT_FENCE();
  float X[9];
  {
    const float4* xr = (const float4*)&Xf8[lane*8];
    float4 xa = xr[0], xb = xr[1];
    X[0]=xa.x; X[1]=xa.y; X[2]=xa.z; X[3]=xa.w;
    X[4]=xb.x; X[5]=xb.y; X[6]=xb.z; X[7]=xb.w;
    X[8]=X8f[lane];
  }
  #pragma unroll
  for (int m = 0; m < 9; ++m) X[m] *= 0.0625f;   // / AVG

  // ---- contraction (f32x4 accumulators -> v_pk_fma_f32 pairs) ----
  const f32x4* U1g = (const f32x4*)U1ws;
  const f32x4* U2g = (const f32x4*)U2ws;
  const f32x4* U3g = (const f32x4*)U3ws;
  f32x4 s1 = zero4, s2 = zero4, s3 = zero4;
  #pragma unroll
  for (int j = 0; j < 9; ++j) s1 += U1g[j] * X[j];
  {
    int t2i = 0;
    #pragma unroll
    for (int j = 0; j < 9; ++j)
      #pragma unroll
      for (int k = j; k < 9; ++k){
        float m = X[j]*X[k];
        s2 += U2g[t2i] * m; ++t2i;
      }
  }
  {
    int t3i = 0;
    #pragma unroll
    for (int i = 0; i < 9; ++i)
      #pragma unroll
      for (int j = i; j < 9; ++j){
        float mij = X[i]*X[j];
        #pragma unroll
        for (int k = j; k < 9; ++k){
          s3 += U3g[t3i] * (mij*X[k]); ++t3i;
        }
      }
  }

  int zn = atom[n];
  float outval = 0.f;
  #pragma unroll
  for (int p = 0; p < 4; ++p){
    int b = (zn*4 + p)*64 + lane;
    outval += ldf(Wc1, b, bf)*s1[p] + ldf(Wc2, b, bf)*s2[p] + ldf(Wc3, b, bf)*s3[p];
  }

  // ---- final matmul (xchg reuses act slice after Xf8 consumed) ----
  float* xchg = (float*)A;
  SOFT_FENCE();
  xchg[lane] = outval;
  SOFT_FENCE();
  float acc = 0.f;
  const float4* pb = (const float4*)xchg;
  if (bf){
    const u16* wg = (const u16*)Woutg;
    #pragma unroll
    for (int cb = 0; cb < 16; ++cb){
      float4 p = pb[cb];
      acc += p.x*bf2f(wg[(4*cb+0)*64 + lane]) + p.y*bf2f(wg[(4*cb+1)*64 + lane])
           + p.z*bf2f(wg[(4*cb+2)*64 + lane]) + p.w*bf2f(wg[(4*cb+3)*64 + lane]);
    }
  } else {
    const float* wg = (const float*)Woutg;
    #pragma unroll
    for (int cb = 0; cb < 16; ++cb){
      float4 p = pb[cb];
      acc += p.x*wg[(4*cb+0)*64 + lane] + p.y*wg[(4*cb+1)*64 + lane]
           + p.z*wg[(4*cb+2)*64 + lane] + p.w*wg[(4*cb+3)*64 + lane];
    }
  }
  acc *= 0.125f;
  if (bf) ((u16*)outp)[n*64 + lane] = f2bf(acc);
  else    ((float*)outp)[n*64 + lane] = acc;
}

// ---------------- host ----------------
extern "C" void kernel_launch(void* const* d_in, const int* in_sizes, int n_in,
                              void* d_out, int out_size, void* d_ws, size_t ws_size,
                              hipStream_t stream)
{
  const void* pos  = d_in[0];
  const int* atom  = (const int*)d_in[1];
  const int* eidx  = (const int*)d_in[2];
  const void* We   = d_in[3];
  const void* Wu   = d_in[4];
  const void* w1g  = d_in[5];
  const void* w2g  = d_in[6];
  const void* w3g  = d_in[7];
  const void* w4g  = d_in[8];
  const void* U3   = d_in[9];
  const void* U2   = d_in[10];
  const void* U1   = d_in[11];
  const void* Wc3  = d_in[12];
  const void* Wc2  = d_in[13];
  const void* Wc1  = d_in[14];
  const void* Wout = d_in[15];

  char* ws = (char*)d_ws;
  float*  Hws   = (float*)(ws + WP_H);
  float*  U1ws  = (float*)(ws + WP_U1);
  float*  U2ws  = (float*)(ws + WP_U2);
  float*  U3ws  = (float*)(ws + WP_U3);
  int*    cur   = (int*)(ws + WP_CUR);
  float4* posf  = (float4*)(ws + WP_POSF);
  u16*    wbws  = (u16*)(ws + WP_WB);
  u16*    el16  = (u16*)(ws + WP_EL16);

  (void)hipMemsetAsync(ws + WP_CUR, 0, 80000, stream);
  k_prep_pad<<<1250, 256, 0, stream>>>(We, Wu, U3, U2, U1, w1g, w2g, w3g, w4g, pos, eidx,
                                       Hws, U3ws, U2ws, U1ws, wbws, posf, cur, el16);
  k_main<<<5000, 256, 0, stream>>>(atom, Wu, Wc3, Wc2, Wc1, Wout,
                                   Hws, U3ws, U2ws, U1ws, posf,
                                   cur, el16, wbws, d_out);
}

// Round 12
// 256.872 us; speedup vs baseline: 2.3214x; 1.0825x over previous
//
#include <hip/hip_runtime.h>
#include <hip/hip_bf16.h>

typedef unsigned short u16;
typedef unsigned int u32;
typedef __attribute__((ext_vector_type(8))) short bf16x8;
typedef __attribute__((ext_vector_type(4))) float f32x4;

#define NN 20000
#define NE 320000

// ---------------- workspace layout (padded CSR; ws_size >= 3,012,224 proven) ----------------
#define WP_H     256       // 640 f32
#define WP_U1    3072      // 36 f32
#define WP_U2    3328      // 180 f32
#define WP_U3    4096      // 660 f32
#define WP_CUR   7168      // 20000 i32 (doubles as deg for k_main)
#define WP_POSF  87168     // 20000 float4
#define WP_WB    407168    // 22528 u16
#define WP_EL16  452224    // 20000*64 u16

__device__ __forceinline__ float bf2f(u16 u){ return __uint_as_float(((u32)u) << 16); }
__device__ __forceinline__ u16 f2bf(float f){
  u32 u = __float_as_uint(f);
  u32 r = (u + 0x7fffu + ((u >> 16) & 1u)) >> 16;
  return (u16)r;
}
__device__ __forceinline__ u16 f2bfa(float f){
  return (u16)((__float_as_uint(f) + 0x8000u) >> 16);
}
__device__ __forceinline__ u32 pk2bf(float a, float b){
  __hip_bfloat162 h = __float22bfloat162_rn(make_float2(a, b));
  return *(u32*)&h;
}
__device__ __forceinline__ float silu_f(float v){
  return v * __builtin_amdgcn_rcpf(1.0f + __expf(-v));
}
__device__ __forceinline__ float ldf(const void* p, int i, int bf){
  return bf ? bf2f(((const u16*)p)[i]) : ((const float*)p)[i];
}
__device__ __forceinline__ f32x4 mfma16(bf16x8 a, bf16x8 b, f32x4 c){
  return __builtin_amdgcn_mfma_f32_16x16x32_bf16(a, b, c, 0, 0, 0);
}

// Compiler-only fence for SAME-WAVE LDS exchange: CDNA DS ops from one wave
// complete in program order, so cross-lane RAW within a wave needs no hardware
// drain — only a compiler reordering barrier. Zero cycles.
#define SOFT_FENCE() do { \
  __builtin_amdgcn_wave_barrier(); \
  asm volatile("" ::: "memory"); \
  __builtin_amdgcn_wave_barrier(); \
} while (0)

__device__ __forceinline__ int sniff_wave(const u32* wu, int lane){
  u32 w = wu[lane];
  u32 e = (w >> 7) & 0xFFu;
  unsigned long long m = __ballot(e >= 0x60u && e <= 0x86u);
  return (__popcll(m) > 37) ? 1 : 0;
}

// ---------------- fused prep (grid=1250) — R18-R20 proven, unchanged ----------------
extern "C" __global__ __launch_bounds__(256)
void k_prep_pad(const void* __restrict__ We, const void* __restrict__ Wu,
                const void* __restrict__ U3, const void* __restrict__ U2, const void* __restrict__ U1,
                const void* __restrict__ w1, const void* __restrict__ w2,
                const void* __restrict__ w3, const void* __restrict__ w4,
                const void* __restrict__ pos, const int* __restrict__ eidx,
                float* __restrict__ Hws, float* __restrict__ U3ws,
                float* __restrict__ U2ws, float* __restrict__ U1ws,
                u16* __restrict__ wbws, float4* __restrict__ posf,
                int* __restrict__ cur, u16* __restrict__ el16)
{
  int tid = threadIdx.x;
  int b = blockIdx.x;
  int bf = sniff_wave((const u32*)Wu, tid & 63);

  // fused padded scatter: one edge per thread (1250*256 = NE)
  {
    int e = b*256 + tid;
    int r = eidx[NE + e];
    int s = eidx[e];
    int slot = atomicAdd(&cur[r], 1);
    if (slot < 64) el16[(r << 6) + slot] = (u16)s;
  }

  if (b == 0){
    for (int t = tid; t < 36; t += 256) U1ws[t] = ldf(U1, t, bf);
    for (int t = tid; t < 45; t += 256){
      int j = 0, rem = t;
      for (;;){ int cnt = 9 - j; if (rem < cnt) break; rem -= cnt; ++j; }
      int k = j + rem;
      for (int p = 0; p < 4; ++p){
        float v = ldf(U2, (j*9 + k)*4 + p, bf);
        if (k > j) v += ldf(U2, (k*9 + j)*4 + p, bf);
        U2ws[t*4 + p] = v;
      }
    }
    for (int t = tid; t < 165; t += 256){
      int i = 0, rem = t;
      for (;;){ int m = 9 - i; int cnt = m*(m+1)/2; if (rem < cnt) break; rem -= cnt; ++i; }
      int j = i;
      for (;;){ int cnt = 9 - j; if (rem < cnt) break; rem -= cnt; ++j; }
      int k = j + rem;
      int pm[6][3] = {{i,j,k},{i,k,j},{j,i,k},{j,k,i},{k,i,j},{k,j,i}};
      float acc[4] = {0,0,0,0};
      for (int m = 0; m < 6; ++m){
        bool dup = false;
        for (int mm = 0; mm < m; ++mm)
          if (pm[mm][0]==pm[m][0] && pm[mm][1]==pm[m][1] && pm[mm][2]==pm[m][2]) dup = true;
        if (!dup){
          int base = ((pm[m][0]*9 + pm[m][1])*9 + pm[m][2])*4;
          for (int p = 0; p < 4; ++p) acc[p] += ldf(U3, base + p, bf);
        }
      }
      for (int p = 0; p < 4; ++p) U3ws[t*4 + p] = acc[p];
    }
  } else if (b <= 88){
    // B-frag pack (16x16x32): lane L holds B[k=(L>>4)*8+j][n=L&15]
    int idx = (b - 1)*256 + tid;
    int f = idx >> 9;
    int L = (idx >> 3) & 63;
    int j = idx & 7;
    int kl = ((L >> 4) << 3) + j;
    int n16 = L & 15;
    float v;
    if (f < 4){
      v = (kl < 8) ? ldf(w1, kl*64 + (f*16 + n16), bf) : 0.f;
    } else if (f < 12){
      int g = f - 4; int t = g >> 1, q = g & 1;
      v = ldf(w2, (q*32 + kl)*64 + (t*16 + n16), bf);
    } else if (f < 20){
      int g = f - 12; int t = g >> 1, q = g & 1;
      v = ldf(w3, (q*32 + kl)*64 + (t*16 + n16), bf);
    } else {
      int g = f - 20; int lt = g >> 1, q = g & 1;
      int l = lt >> 2, ct = lt & 3;
      v = ldf(w4, (q*32 + kl)*192 + (l*64 + ct*16 + n16), bf);
    }
    wbws[idx] = f2bf(v);
  } else if (b <= 167){
    int i = (b - 89)*256 + tid;
    if (i < NN){
      float4 v;
      v.x = ldf(pos, 3*i+0, bf); v.y = ldf(pos, 3*i+1, bf); v.z = ldf(pos, 3*i+2, bf); v.w = 0.f;
      posf[i] = v;
    }
  } else if (b <= 177){
    int z = b - 168;
    int c = tid;
    if (c < 64){
      float s = 0.f;
      for (int k = 0; k < 64; ++k) s += ldf(We, z*64 + k, bf) * ldf(Wu, k*64 + c, bf);
      Hws[z*64 + c] = s * 0.0395284708f;   // 1/sqrt(Z*C)
    }
  }
}

// ---------------- edge geometry ----------------
__device__ __forceinline__ void edge_geom(float4 pr, float4 ps, float* ef, float* Y)
{
  float vx = pr.x - ps.x, vy = pr.y - ps.y, vz = pr.z - ps.z;
  float r2 = vx*vx + vy*vy + vz*vz + 1e-12f;
  float rinv = rsqrtf(r2);
  float r = r2 * rinv;
  float ux = vx*rinv, uy = vy*rinv, uz = vz*rinv;
  const float s3 = 1.7320508076f, s5 = 2.2360679775f, s15 = 3.8729833462f;
  Y[0] = 1.0f;
  Y[1] = s3*ux; Y[2] = s3*uy; Y[3] = s3*uz;
  Y[4] = s15*ux*uy; Y[5] = s15*uy*uz;
  Y[6] = 0.5f*s5*(3.0f*uz*uz - 1.0f);
  Y[7] = s15*ux*uz;
  Y[8] = 0.5f*s15*(ux*ux - uy*uy);
  float u = r * 0.2f; u = fminf(u, 1.0f);
  float u2 = u*u, u4 = u2*u2, u6 = u4*u2, u7 = u6*u, u8 = u7*u;
  float fc = 1.0f - 28.0f*u6 + 48.0f*u7 - 21.0f*u8;
  float c0 = 0.63245553203f * fc * rinv;
  float w = 0.62831853072f * r;
  #pragma unroll
  for (int k = 0; k < 8; ++k) ef[k] = c0 * __sinf(w * (float)(k + 1));
}

// ---------------- main: MFMA edge-tile MLP ----------------
// R30: R29 (best verified: 185.8 us, VGPR 80, ZERO spill) + w3 de-hoisted too.
// R29's post-mortem refined the occupancy model: 4 blocks/CU needs
// archVGPR + AGPR <= 128; AGPR is evidently 56-64 (R23: arch 64 -> 4 blocks;
// R29: arch 80 -> 3 blocks). De-hoisting w3p (-32 arch) via the same
// opaque-SGPR-offset trick that R29 proved spill-free should land arch at
// ~56-64 -> total <= 128 -> 4 waves/SIMD. Cost: +8 L1-hot loads/tile, better
// hidden at 16 waves/CU.
// PRE-COMMIT: VGPR<=64 but occupancy ~28% -> model wrong, structural write-up
// next. Dur regression despite 4 blocks -> extra loads outweigh, R29 final.
// Not a roofline yet: HBM 1%, MfmaUtil 5.8% — latency-bound plateau.
extern "C" __global__ __launch_bounds__(256, 3)
void k_main(const int* __restrict__ atom,
            const void* __restrict__ Wu,
            const void* __restrict__ Wc3, const void* __restrict__ Wc2, const void* __restrict__ Wc1,
            const void* __restrict__ Woutg,
            const float* __restrict__ Hws, const float* __restrict__ U3ws,
            const float* __restrict__ U2ws, const float* __restrict__ U1ws,
            const float4* __restrict__ posf,
            const int* __restrict__ deg, const u16* __restrict__ el16,
            const u16* __restrict__ wbws, void* __restrict__ outp)
{
  __shared__ __align__(16) u16   wb[12288];        // 24576 B  24 w4 B-frags (block-shared)
  __shared__ __align__(16) u16   act[4][1024];     // 8192 B   swizzled [16][64]; pfrag/Xf8/xchg alias
  __shared__ __align__(16) u16   efb[4][64][8];    // 4096 B   ef; X8f aliases here
  __shared__ __align__(16) u16   Yc8[4][64][8];    // 4096 B   Y[1..8] compact
  // total 40,960 B -> 4 blocks/CU by LDS

  int tid = threadIdx.x;
  int wv = tid >> 6;
  int lane = tid & 63;
  int bf = sniff_wave((const u32*)Wu, lane);

  int c0 = lane & 15;
  int qd = lane >> 4;
  int n = blockIdx.x * 4 + wv;

  // ---- gather chain issued ASAP (latency hides under staging) ----
  int cnt = min(deg[n], 64);
  int el  = (int)el16[(n << 6) + lane];   // padded row, always safe
  float4 pr = posf[n];

  // stage w4 frags (orig frag 20..43 -> uint4 offset 1280) as b128 copies
  for (int t = tid; t < 1536; t += 256)
    ((uint4*)wb)[t] = ((const uint4*)wbws)[1280 + t];

  bool valid = lane < cnt;
  int sid = valid ? el : n;
  float4 ps = posf[sid];
  int zreg = valid ? atom[sid] : 0;

  // ---- geometry + per-wave LDS writes (efb/Yc8 disjoint from wb) ----
  {
    float ef[8], Y[9];
    edge_geom(pr, ps, ef, Y);
    if (!valid){
      #pragma unroll
      for (int k = 0; k < 8; ++k) ef[k] = 0.f;
      #pragma unroll
      for (int m = 0; m < 9; ++m) Y[m] = 0.f;
    }
    uint4 pk;
    pk.x = pk2bf(ef[0], ef[1]);
    pk.y = pk2bf(ef[2], ef[3]);
    pk.z = pk2bf(ef[4], ef[5]);
    pk.w = pk2bf(ef[6], ef[7]);
    *(uint4*)&efb[wv][lane][0] = pk;
    uint4 yp;
    yp.x = pk2bf(Y[1], Y[2]);
    yp.y = pk2bf(Y[3], Y[4]);
    yp.z = pk2bf(Y[5], Y[6]);
    yp.w = pk2bf(Y[7], Y[8]);
    *(uint4*)&Yc8[wv][lane][0] = yp;
  }
  __syncthreads();   // covers wb staging AND per-wave efb/Yc8 writes

  u16* A = &act[wv][0];
  int swr = qd << 4;            // write swizzle: row = qd*4+r -> row>>2 == qd
  int srd = (c0 >> 2) << 4;     // read swizzle:  row = c0

  int lmap = (c0 == 0) ? 0 : (c0 < 4) ? 1 : 2;
  u32 msk1 = (lmap == 1) ? 0xFFFFFFFFu : 0u;
  u32 msk2 = (lmap == 2) ? 0xFFFFFFFFu : 0u;

  const f32x4 zero4 = {0.f, 0.f, 0.f, 0.f};
  f32x4 XD[4];
  #pragma unroll
  for (int t = 0; t < 4; ++t) XD[t] = zero4;

  int prow = ((qd >> 1) << 4) + c0;
  int pcol = (qd & 1) << 2;
  int ntile = (cnt + 15) >> 4;

  u32 zofs = 0;   // opaque offset: defeats LICM so w1/w2/w3 loads re-issue per tile

  #pragma unroll 1
  for (int t = 0; t < ntile; ++t){
    asm volatile("" : "+s"(zofs));
    f32x4 dd[4];

    // ---- L1 (w1 frags from L1-hot global, not hoisted) ----
    bf16x8 aF = {0,0,0,0,0,0,0,0};
    if (lane < 16) aF = *(const bf16x8*)&efb[wv][t*16 + lane][0];
    #pragma unroll
    for (int t2 = 0; t2 < 4; ++t2){
      bf16x8 w1f = *(const bf16x8*)&wbws[zofs + t2*512 + lane*8];
      dd[t2] = mfma16(aF, w1f, zero4);
    }
    #pragma unroll
    for (int t2 = 0; t2 < 4; ++t2)
      #pragma unroll
      for (int r = 0; r < 4; ++r)
        A[(((qd*4 + r) << 6) + c0 + (t2 << 4)) ^ swr] = f2bfa(silu_f(dd[t2][r]));
    SOFT_FENCE();

    // ---- L2 (w2 frags from L1-hot global, not hoisted) ----
    bf16x8 a0 = *(const bf16x8*)&A[((c0 << 6) + (qd << 3)) ^ srd];
    bf16x8 a1 = *(const bf16x8*)&A[((c0 << 6) + 32 + (qd << 3)) ^ srd];
    #pragma unroll
    for (int t2 = 0; t2 < 4; ++t2){
      bf16x8 w2a = *(const bf16x8*)&wbws[zofs + (4 + t2*2)*512 + lane*8];
      bf16x8 w2b = *(const bf16x8*)&wbws[zofs + (5 + t2*2)*512 + lane*8];
      dd[t2] = mfma16(a1, w2b, mfma16(a0, w2a, zero4));
    }
    #pragma unroll
    for (int t2 = 0; t2 < 4; ++t2)
      #pragma unroll
      for (int r = 0; r < 4; ++r)
        A[(((qd*4 + r) << 6) + c0 + (t2 << 4)) ^ swr] = f2bfa(silu_f(dd[t2][r]));
    SOFT_FENCE();

    // ---- L3 (w3 frags from L1-hot global, not hoisted) ----
    a0 = *(const bf16x8*)&A[((c0 << 6) + (qd << 3)) ^ srd];
    a1 = *(const bf16x8*)&A[((c0 << 6) + 32 + (qd << 3)) ^ srd];
    #pragma unroll
    for (int t2 = 0; t2 < 4; ++t2){
      bf16x8 w3a = *(const bf16x8*)&wbws[zofs + (12 + t2*2)*512 + lane*8];
      bf16x8 w3b = *(const bf16x8*)&wbws[zofs + (13 + t2*2)*512 + lane*8];
      dd[t2] = mfma16(a1, w3b, mfma16(a0, w3a, zero4));
    }
    #pragma unroll
    for (int t2 = 0; t2 < 4; ++t2)
      #pragma unroll
      for (int r = 0; r < 4; ++r)
        A[(((qd*4 + r) << 6) + c0 + (t2 << 4)) ^ swr] = f2bfa(silu_f(dd[t2][r]));
    SOFT_FENCE();

    // ---- L4 + X-MFMA ----
    a0 = *(const bf16x8*)&A[((c0 << 6) + (qd << 3)) ^ srd];
    a1 = *(const bf16x8*)&A[((c0 << 6) + 32 + (qd << 3)) ^ srd];

    // Y B-frag rebuild: Yc8 holds m=1..8; m=0 column = 1.0 * (row < cnt)
    u32 yd0 = 0, yd1 = 0, yd2 = 0, yd3 = 0;
    if (lane < 32 && c0 >= 1 && c0 <= 8){
      const u16* yr = &Yc8[wv][t*16 + ((lane >> 4) << 3)][c0 - 1];
      yd0 = (u32)yr[0*8] | ((u32)yr[1*8] << 16);
      yd1 = (u32)yr[2*8] | ((u32)yr[3*8] << 16);
      yd2 = (u32)yr[4*8] | ((u32)yr[5*8] << 16);
      yd3 = (u32)yr[6*8] | ((u32)yr[7*8] << 16);
    }
    u32 b00 = 0, b01 = 0, b02 = 0, b03 = 0;
    if (lane < 32 && c0 == 0){
      int k0 = t*16 + ((lane >> 4) << 3);
      b00 = ((k0+0 < cnt) ? 0x3F80u : 0u) | ((k0+1 < cnt) ? 0x3F800000u : 0u);
      b01 = ((k0+2 < cnt) ? 0x3F80u : 0u) | ((k0+3 < cnt) ? 0x3F800000u : 0u);
      b02 = ((k0+4 < cnt) ? 0x3F80u : 0u) | ((k0+5 < cnt) ? 0x3F800000u : 0u);
      b03 = ((k0+6 < cnt) ? 0x3F80u : 0u) | ((k0+7 < cnt) ? 0x3F800000u : 0u);
    }
    bf16x8 B0, B1, B2;
    { uint4 t0 = {b00, b01, b02, b03};
      uint4 t1 = {yd0 & msk1, yd1 & msk1, yd2 & msk1, yd3 & msk1};
      uint4 t2 = {yd0 & msk2, yd1 & msk2, yd2 & msk2, yd3 & msk2};
      B0 = *(bf16x8*)&t0; B1 = *(bf16x8*)&t1; B2 = *(bf16x8*)&t2; }

    float hv[4][4];
    #pragma unroll
    for (int r = 0; r < 4; ++r){
      int z_e = __shfl(zreg, t*16 + qd*4 + r);
      #pragma unroll
      for (int ct = 0; ct < 4; ++ct) hv[r][ct] = Hws[z_e*64 + ct*16 + c0];
    }

    u16* PF = A;   // pfrag aliases act: [ct][32][8] u16 = 2048 B per wave
    #pragma unroll
    for (int l = 0; l < 3; ++l){
      #pragma unroll
      for (int ct = 0; ct < 4; ++ct){
        int f = (l*4 + ct)*2;
        bf16x8 b0 = *(const bf16x8*)&wb[f*512 + lane*8];
        bf16x8 b1 = *(const bf16x8*)&wb[(f+1)*512 + lane*8];
        dd[ct] = mfma16(a1, b1, mfma16(a0, b0, zero4));
      }
      #pragma unroll
      for (int ct = 0; ct < 4; ++ct){
        uint2 pk2;
        pk2.x = pk2bf(hv[0][ct] * dd[ct][0], hv[1][ct] * dd[ct][1]);
        pk2.y = pk2bf(hv[2][ct] * dd[ct][2], hv[3][ct] * dd[ct][3]);
        *(uint2*)&PF[ct*256 + prow*8 + pcol] = pk2;
      }
      SOFT_FENCE();
      bf16x8 Bl = (l == 0) ? B0 : (l == 1) ? B1 : B2;
      #pragma unroll
      for (int ct = 0; ct < 4; ++ct){
        bf16x8 aP = {0,0,0,0,0,0,0,0};
        if (lane < 32) aP = *(const bf16x8*)&PF[ct*256 + lane*8];
        XD[ct] = mfma16(aP, Bl, XD[ct]);
      }
      SOFT_FENCE();
    }
  }

  // ---- redistribute X: D-frags -> Xf8 (act slice) + X8f (efb slice) ----
  float* Xf8 = (float*)A;                 // [64][8] f32 = 2048 B
  float* X8f = (float*)&efb[wv][0][0];    // [64] f32 = 256 B
  SOFT_FENCE();
  #pragma unroll
  for (int ct = 0; ct < 4; ++ct)
    #pragma unroll
    for (int r = 0; r < 4; ++r){
      int c = ct*16 + qd*4 + r;
      if (c0 < 8)       Xf8[c*8 + c0] = XD[ct][r];
      else if (c0 == 8) X8f[c]        = XD[ct][r];
    }
  SOFT_FENCE();
  float X[9];
  {
    const float4* xr = (const float4*)&Xf8[lane*8];
    float4 xa = xr[0], xb = xr[1];
    X[0]=xa.x; X[1]=xa.y; X[2]=xa.z; X[3]=xa.w;
    X[4]=xb.x; X[5]=xb.y; X[6]=xb.z; X[7]=xb.w;
    X[8]=X8f[lane];
  }
  #pragma unroll
  for (int m = 0; m < 9; ++m) X[m] *= 0.0625f;   // / AVG

  // ---- contraction (f32x4 accumulators -> v_pk_fma_f32 pairs) ----
  const f32x4* U1g = (const f32x4*)U1ws;
  const f32x4* U2g = (const f32x4*)U2ws;
  const f32x4* U3g = (const f32x4*)U3ws;
  f32x4 s1 = zero4, s2 = zero4, s3 = zero4;
  #pragma unroll
  for (int j = 0; j < 9; ++j) s1 += U1g[j] * X[j];
  {
    int t2i = 0;
    #pragma unroll
    for (int j = 0; j < 9; ++j)
      #pragma unroll
      for (int k = j; k < 9; ++k){
        float m = X[j]*X[k];
        s2 += U2g[t2i] * m; ++t2i;
      }
  }
  {
    int t3i = 0;
    #pragma unroll
    for (int i = 0; i < 9; ++i)
      #pragma unroll
      for (int j = i; j < 9; ++j){
        float mij = X[i]*X[j];
        #pragma unroll
        for (int k = j; k < 9; ++k){
          s3 += U3g[t3i] * (mij*X[k]); ++t3i;
        }
      }
  }

  int zn = atom[n];
  float outval = 0.f;
  #pragma unroll
  for (int p = 0; p < 4; ++p){
    int b = (zn*4 + p)*64 + lane;
    outval += ldf(Wc1, b, bf)*s1[p] + ldf(Wc2, b, bf)*s2[p] + ldf(Wc3, b, bf)*s3[p];
  }

  // ---- final matmul (xchg reuses act slice after Xf8 consumed) ----
  float* xchg = (float*)A;
  SOFT_FENCE();
  xchg[lane] = outval;
  SOFT_FENCE();
  float acc = 0.f;
  const float4* pb = (const float4*)xchg;
  if (bf){
    const u16* wg = (const u16*)Woutg;
    #pragma unroll
    for (int cb = 0; cb < 16; ++cb){
      float4 p = pb[cb];
      acc += p.x*bf2f(wg[(4*cb+0)*64 + lane]) + p.y*bf2f(wg[(4*cb+1)*64 + lane])
           + p.z*bf2f(wg[(4*cb+2)*64 + lane]) + p.w*bf2f(wg[(4*cb+3)*64 + lane]);
    }
  } else {
    const float* wg = (const float*)Woutg;
    #pragma unroll
    for (int cb = 0; cb < 16; ++cb){
      float4 p = pb[cb];
      acc += p.x*wg[(4*cb+0)*64 + lane] + p.y*wg[(4*cb+1)*64 + lane]
           + p.z*wg[(4*cb+2)*64 + lane] + p.w*wg[(4*cb+3)*64 + lane];
    }
  }
  acc *= 0.125f;
  if (bf) ((u16*)outp)[n*64 + lane] = f2bf(acc);
  else    ((float*)outp)[n*64 + lane] = acc;
}

// ---------------- host ----------------
extern "C" void kernel_launch(void* const* d_in, const int* in_sizes, int n_in,
                              void* d_out, int out_size, void* d_ws, size_t ws_size,
                              hipStream_t stream)
{
  const void* pos  = d_in[0];
  const int* atom  = (const int*)d_in[1];
  const int* eidx  = (const int*)d_in[2];
  const void* We   = d_in[3];
  const void* Wu   = d_in[4];
  const void* w1g  = d_in[5];
  const void* w2g  = d_in[6];
  const void* w3g  = d_in[7];
  const void* w4g  = d_in[8];
  const void* U3   = d_in[9];
  const void* U2   = d_in[10];
  const void* U1   = d_in[11];
  const void* Wc3  = d_in[12];
  const void* Wc2  = d_in[13];
  const void* Wc1  = d_in[14];
  const void* Wout = d_in[15];

  char* ws = (char*)d_ws;
  float*  Hws   = (float*)(ws + WP_H);
  float*  U1ws  = (float*)(ws + WP_U1);
  float*  U2ws  = (float*)(ws + WP_U2);
  float*  U3ws  = (float*)(ws + WP_U3);
  int*    cur   = (int*)(ws + WP_CUR);
  float4* posf  = (float4*)(ws + WP_POSF);
  u16*    wbws  = (u16*)(ws + WP_WB);
  u16*    el16  = (u16*)(ws + WP_EL16);

  (void)hipMemsetAsync(ws + WP_CUR, 0, 80000, stream);
  k_prep_pad<<<1250, 256, 0, stream>>>(We, Wu, U3, U2, U1, w1g, w2g, w3g, w4g, pos, eidx,
                                       Hws, U3ws, U2ws, U1ws, wbws, posf, cur, el16);
  k_main<<<5000, 256, 0, stream>>>(atom, Wu, Wc3, Wc2, Wc1, Wout,
                                   Hws, U3ws, U2ws, U1ws, posf,
                                   cur, el16, wbws, d_out);
}